// Round 8
// baseline (235.092 us; speedup 1.0000x reference)
//
#include <hip/hip_runtime.h>

// GraphSAGE 2-layer + classifier on MI355X (gfx950).
// Wave-per-node gathers (fabric-floor bound), MFMA GEMMs, lean bucket CSR.
//
//   memset bcnt|bcur = 0
//   k_lin1d_bcount: blocks [0,gtiles): t1,r1 = bf16(x @ {W1l,W1r}.T)
//                   blocks [gtiles, +NWG): LDS histogram of dst>>7 -> bcnt
//   k_bscatter: per-WG scan of bcnt -> bases; stage chunk; reserve bucket runs
//               (bucket-relative atomics on zero-init bcur); emit packed edges
//   k_bcsr: one WG per 128-node bucket: e0 via bcnt reduce; LDS degree count +
//           scan -> rowptr; col scatter (writes in an 8KB window)
//   k_aggh1: wave/node: h1 = bf16(relu(gather-sum(t1)/deg + r1 + b1))
//   k_lin2:  y2,r2 = bf16(h1 @ [W2l;W2r].T)
//   k_agghead: wave/node: logit = relu(gather-sum(y2)/deg + r2 + b2).Wc + bc

static constexpr int TPB = 256;
static constexpr int NWG = 512;    // edge-chunk workgroups
static constexpr int ECMAX = 3200; // >= E/NWG = 3125
static constexpr int NBMAX = 1024; // >= ceil(N/128) = 782

typedef __attribute__((ext_vector_type(8))) short bf16x8;
typedef __attribute__((ext_vector_type(4))) float f32x4;

__device__ __forceinline__ unsigned short f2bf(float f) {
  union { float f; unsigned u; } v; v.f = f;
  unsigned r = v.u + 0x7FFFu + ((v.u >> 16) & 1u);  // RNE
  return (unsigned short)(r >> 16);
}
__device__ __forceinline__ float bf2f(unsigned short h) {
  union { unsigned u; float f; } v; v.u = ((unsigned)h) << 16;
  return v.f;
}

// ---------------- bf16 MFMA GEMM pieces ----------------
static constexpr int LD = 136;  // padded bf16 leading dim (2-way aliasing = free)

__device__ __forceinline__ void mfma_tile_128(
    const unsigned short* As, const unsigned short* Bs,
    unsigned short* __restrict__ out, int row0, int N, int w, int l) {
  int lr = l & 15, lk = l >> 4;
  f32x4 acc[4][2];
#pragma unroll
  for (int mb = 0; mb < 4; ++mb)
#pragma unroll
    for (int nb = 0; nb < 2; ++nb)
#pragma unroll
      for (int q = 0; q < 4; ++q) acc[mb][nb][q] = 0.f;
#pragma unroll
  for (int ks = 0; ks < 4; ++ks) {
    int koff = ks * 32 + lk * 8;
    bf16x8 a[4], bfr[2];
#pragma unroll
    for (int mb = 0; mb < 4; ++mb)
      a[mb] = *(const bf16x8*)&As[(mb * 16 + lr) * LD + koff];
#pragma unroll
    for (int nb = 0; nb < 2; ++nb)
      bfr[nb] = *(const bf16x8*)&Bs[(w * 32 + nb * 16 + lr) * LD + koff];
#pragma unroll
    for (int mb = 0; mb < 4; ++mb)
#pragma unroll
      for (int nb = 0; nb < 2; ++nb)
        acc[mb][nb] = __builtin_amdgcn_mfma_f32_16x16x32_bf16(a[mb], bfr[nb], acc[mb][nb], 0, 0, 0);
  }
#pragma unroll
  for (int mb = 0; mb < 4; ++mb) {
    int r = row0 + mb * 16 + lk * 4;
#pragma unroll
    for (int nb = 0; nb < 2; ++nb) {
      int c = w * 32 + nb * 16 + lr;
#pragma unroll
      for (int j = 0; j < 4; ++j)
        if (r + j < N) out[(size_t)(r + j) * 128 + c] = f2bf(acc[mb][nb][j]);
    }
  }
}

// ---------------- fused layer-1 dual GEMM + bucket count --------------------
__global__ __launch_bounds__(TPB) void k_lin1d_bcount(
    const float* __restrict__ X, const float* __restrict__ W1l,
    const float* __restrict__ W1r, unsigned short* __restrict__ t1,
    unsigned short* __restrict__ r1, int N,
    const int* __restrict__ dst, int* __restrict__ bcnt,
    int E, int NB, int EC, int gtiles) {
  __shared__ unsigned short Bs[128 * LD];
  __shared__ unsigned short As[64 * LD];
  int bid = blockIdx.x;
  int t = threadIdx.x;
  if (bid >= gtiles) {
    // ---- bcount role: LDS histogram of dst>>7, flush with NB atomics ----
    int* lhist = (int*)Bs;  // 782*4 B <= sizeof(Bs)
    for (int b = t; b < NB; b += TPB) lhist[b] = 0;
    __syncthreads();
    int base = (bid - gtiles) * EC;
    int cnt = min(EC, E - base);
    for (int i = t; i < cnt; i += TPB)
      atomicAdd(&lhist[dst[base + i] >> 7], 1);
    __syncthreads();
    for (int b = t; b < NB; b += TPB) {
      int c = lhist[b];
      if (c) atomicAdd(&bcnt[b], c);
    }
    return;
  }
  // ---- lin1d role: stage x once, run W1l then W1r ----
  int row0 = bid * 64;
  for (int i = t; i < 64 * 32; i += TPB) {
    int r = i >> 5, k4 = i & 31;
    int gr = row0 + r;
    float4 v;
    if (gr < N) v = *(const float4*)&X[(size_t)gr * 128 + k4 * 4];
    else { v.x = v.y = v.z = v.w = 0.f; }
    ushort4 o; o.x = f2bf(v.x); o.y = f2bf(v.y); o.z = f2bf(v.z); o.w = f2bf(v.w);
    *(ushort4*)&As[r * LD + k4 * 4] = o;
  }
  for (int i = t; i < 128 * 32; i += TPB) {
    int r = i >> 5, k4 = i & 31;
    float4 v = *(const float4*)&W1l[r * 128 + k4 * 4];
    ushort4 o; o.x = f2bf(v.x); o.y = f2bf(v.y); o.z = f2bf(v.z); o.w = f2bf(v.w);
    *(ushort4*)&Bs[r * LD + k4 * 4] = o;
  }
  __syncthreads();
  int w = t >> 6, l = t & 63;
  mfma_tile_128(As, Bs, t1, row0, N, w, l);
  __syncthreads();
  for (int i = t; i < 128 * 32; i += TPB) {
    int r = i >> 5, k4 = i & 31;
    float4 v = *(const float4*)&W1r[r * 128 + k4 * 4];
    ushort4 o; o.x = f2bf(v.x); o.y = f2bf(v.y); o.z = f2bf(v.z); o.w = f2bf(v.w);
    *(ushort4*)&Bs[r * LD + k4 * 4] = o;
  }
  __syncthreads();
  mfma_tile_128(As, Bs, r1, row0, N, w, l);
}

// ---------------- bucket scatter (self-scanned bases, packed 4B edges) ------
__global__ __launch_bounds__(TPB) void k_bscatter(
    const int* __restrict__ src, const int* __restrict__ dst,
    const int* __restrict__ bcnt, int* __restrict__ bcur,
    int* __restrict__ ebuf, int E, int NB, int EC) {
  __shared__ int pv[ECMAX];
  __shared__ unsigned short kb[ECMAX];
  __shared__ int sb[NBMAX];     // exclusive scan of bcnt (bucket bases)
  __shared__ int lhist[NBMAX];
  __shared__ int lcur[NBMAX];
  __shared__ int sp[TPB];
  int t = threadIdx.x;
  // exclusive scan of bcnt: thread t owns elements [4t, 4t+4)
  int loc[4]; int ssum = 0;
#pragma unroll
  for (int q = 0; q < 4; ++q) {
    int idx = t * 4 + q;
    loc[q] = (idx < NB) ? bcnt[idx] : 0;
    ssum += loc[q];
  }
  sp[t] = ssum; __syncthreads();
  for (int off = 1; off < TPB; off <<= 1) {
    int x = (t >= off) ? sp[t - off] : 0;
    __syncthreads();
    sp[t] += x;
    __syncthreads();
  }
  int run = sp[t] - ssum;
#pragma unroll
  for (int q = 0; q < 4; ++q) {
    int idx = t * 4 + q;
    if (idx < NB) sb[idx] = run;
    run += loc[q];
  }
  for (int b = t; b < NB; b += TPB) lhist[b] = 0;
  int base = blockIdx.x * EC;
  int cnt = min(EC, E - base);
  __syncthreads();
  for (int i = t; i < cnt; i += TPB) {
    int sv = src[base + i], dv = dst[base + i];
    int b = dv >> 7;
    kb[i] = (unsigned short)b;
    pv[i] = ((dv & 127) << 17) | sv;
    atomicAdd(&lhist[b], 1);
  }
  __syncthreads();
  for (int b = t; b < NB; b += TPB) {
    int c = lhist[b];
    lcur[b] = c ? (sb[b] + atomicAdd(&bcur[b], c)) : 0;
  }
  __syncthreads();
  for (int i = t; i < cnt; i += TPB) {
    int b = kb[i];
    int pos = atomicAdd(&lcur[b], 1);
    ebuf[pos] = pv[i];
  }
}

// ---------------- per-bucket CSR finalize (128 nodes per WG) ----------------
__global__ __launch_bounds__(TPB) void k_bcsr(
    const int* __restrict__ ebuf, const int* __restrict__ bcnt,
    int* __restrict__ rowptr, int* __restrict__ col, int N, int NB) {
  __shared__ int deg[128], sscan[128], lcur[128], red[TPB];
  int b = blockIdx.x, t = threadIdx.x;
  int part = 0;
  for (int i = t; i < b; i += TPB) part += bcnt[i];
  red[t] = part; __syncthreads();
  for (int off = TPB / 2; off > 0; off >>= 1) {
    if (t < off) red[t] += red[t + off];
    __syncthreads();
  }
  int e0 = red[0];
  int e1 = e0 + bcnt[b];
  if (t < 128) deg[t] = 0;
  __syncthreads();
  for (int i = e0 + t; i < e1; i += TPB)
    atomicAdd(&deg[ebuf[i] >> 17], 1);
  __syncthreads();
  if (t < 128) sscan[t] = deg[t];
  __syncthreads();
  for (int off = 1; off < 128; off <<= 1) {
    int x = 0;
    if (t < 128 && t >= off) x = sscan[t - off];
    __syncthreads();
    if (t < 128) sscan[t] += x;
    __syncthreads();
  }
  if (t < 128) {
    int excl = sscan[t] - deg[t];
    int node0 = (b << 7) + t;
    if (node0 < N) rowptr[node0] = e0 + excl;
    lcur[t] = e0 + excl;
  }
  if (b == NB - 1 && t == 0) rowptr[N] = e1;
  __syncthreads();
  for (int i = e0 + t; i < e1; i += TPB) {
    int pvv = ebuf[i];
    int pos = atomicAdd(&lcur[pvv >> 17], 1);
    col[pos] = pvv & 0x1FFFF;
  }
}

// ---------------- gather + h1 (wave per node, 4-deep unroll) ----------------
__global__ void k_aggh1(const unsigned short* __restrict__ t1,
                        const unsigned short* __restrict__ r1,
                        const int* __restrict__ rowptr, const int* __restrict__ col,
                        const float* __restrict__ b1,
                        unsigned short* __restrict__ h1, int n) {
  int wid = (int)(((size_t)blockIdx.x * blockDim.x + threadIdx.x) >> 6);
  int l = threadIdx.x & 63;
  if (wid >= n) return;
  int rp0 = rowptr[wid], rp1 = rowptr[wid + 1];
  int g = l >> 4, s = l & 15;
  float acc[8];
#pragma unroll
  for (int q = 0; q < 8; ++q) acc[q] = 0.f;
  int j = rp0 + g;
  for (; j + 12 < rp1; j += 16) {
    int c0 = col[j], c1 = col[j + 4], c2 = col[j + 8], c3 = col[j + 12];
    bf16x8 v0 = *(const bf16x8*)&t1[(size_t)c0 * 128 + s * 8];
    bf16x8 v1 = *(const bf16x8*)&t1[(size_t)c1 * 128 + s * 8];
    bf16x8 v2 = *(const bf16x8*)&t1[(size_t)c2 * 128 + s * 8];
    bf16x8 v3 = *(const bf16x8*)&t1[(size_t)c3 * 128 + s * 8];
#pragma unroll
    for (int q = 0; q < 8; ++q)
      acc[q] += (bf2f((unsigned short)v0[q]) + bf2f((unsigned short)v1[q])) +
                (bf2f((unsigned short)v2[q]) + bf2f((unsigned short)v3[q]));
  }
  for (; j + 4 < rp1; j += 8) {
    int c0 = col[j], c1 = col[j + 4];
    bf16x8 v0 = *(const bf16x8*)&t1[(size_t)c0 * 128 + s * 8];
    bf16x8 v1 = *(const bf16x8*)&t1[(size_t)c1 * 128 + s * 8];
#pragma unroll
    for (int q = 0; q < 8; ++q)
      acc[q] += bf2f((unsigned short)v0[q]) + bf2f((unsigned short)v1[q]);
  }
  if (j < rp1) {
    int c0 = col[j];
    bf16x8 v0 = *(const bf16x8*)&t1[(size_t)c0 * 128 + s * 8];
#pragma unroll
    for (int q = 0; q < 8; ++q) acc[q] += bf2f((unsigned short)v0[q]);
  }
#pragma unroll
  for (int q = 0; q < 8; ++q) {
    acc[q] += __shfl_xor(acc[q], 16, 64);
    acc[q] += __shfl_xor(acc[q], 32, 64);
  }
  if (g == 0) {
    int d = rp1 - rp0;
    float inv = 1.f / (float)(d > 1 ? d : 1);
    bf16x8 rr = *(const bf16x8*)&r1[(size_t)wid * 128 + s * 8];
    float4 bb0 = *(const float4*)&b1[s * 8];
    float4 bb1 = *(const float4*)&b1[s * 8 + 4];
    float bbv[8] = {bb0.x, bb0.y, bb0.z, bb0.w, bb1.x, bb1.y, bb1.z, bb1.w};
    bf16x8 o;
#pragma unroll
    for (int q = 0; q < 8; ++q) {
      float h = acc[q] * inv + bf2f((unsigned short)rr[q]) + bbv[q];
      h = h > 0.f ? h : 0.f;
      o[q] = (short)f2bf(h);
    }
    *(bf16x8*)&h1[(size_t)wid * 128 + s * 8] = o;
  }
}

// layer-2 pure GEMM: y2,r2 = bf16(h1 @ [W2l;W2r].T)
__global__ __launch_bounds__(TPB) void k_lin2(
    const unsigned short* __restrict__ h1,
    const float* __restrict__ W2l, const float* __restrict__ W2r,
    unsigned short* __restrict__ y2, unsigned short* __restrict__ r2, int N) {
  __shared__ unsigned short Bs[128 * LD];
  __shared__ unsigned short As[64 * LD];
  int t = threadIdx.x;
  for (int i = t; i < 128 * 32; i += TPB) {  // B rows 0-63: W2l, 64-127: W2r
    int r = i >> 5, k4 = i & 31;
    const float* srcp = (r < 64) ? &W2l[(size_t)r * 128 + k4 * 4]
                                 : &W2r[(size_t)(r - 64) * 128 + k4 * 4];
    float4 v = *(const float4*)srcp;
    ushort4 o; o.x = f2bf(v.x); o.y = f2bf(v.y); o.z = f2bf(v.z); o.w = f2bf(v.w);
    *(ushort4*)&Bs[r * LD + k4 * 4] = o;
  }
  int row0 = blockIdx.x * 64;
  for (int i = t * 8; i < 64 * 128; i += TPB * 8) {
    int r = i >> 7, k8 = i & 127;
    int gr = row0 + r;
    bf16x8 v;
    if (gr < N) v = *(const bf16x8*)&h1[(size_t)gr * 128 + k8];
    else { for (int q = 0; q < 8; ++q) v[q] = 0; }
    *(bf16x8*)&As[r * LD + k8] = v;
  }
  __syncthreads();
  int w = t >> 6, l = t & 63;
  int lr = l & 15, lk = l >> 4;
  f32x4 acc[4][2];
#pragma unroll
  for (int mb = 0; mb < 4; ++mb)
#pragma unroll
    for (int nb = 0; nb < 2; ++nb)
#pragma unroll
      for (int q = 0; q < 4; ++q) acc[mb][nb][q] = 0.f;
#pragma unroll
  for (int ks = 0; ks < 4; ++ks) {
    int koff = ks * 32 + lk * 8;
    bf16x8 a[4], bfr[2];
#pragma unroll
    for (int mb = 0; mb < 4; ++mb)
      a[mb] = *(const bf16x8*)&As[(mb * 16 + lr) * LD + koff];
#pragma unroll
    for (int nb = 0; nb < 2; ++nb)
      bfr[nb] = *(const bf16x8*)&Bs[(w * 32 + nb * 16 + lr) * LD + koff];
#pragma unroll
    for (int mb = 0; mb < 4; ++mb)
#pragma unroll
      for (int nb = 0; nb < 2; ++nb)
        acc[mb][nb] = __builtin_amdgcn_mfma_f32_16x16x32_bf16(a[mb], bfr[nb], acc[mb][nb], 0, 0, 0);
  }
#pragma unroll
  for (int mb = 0; mb < 4; ++mb) {
    int r = row0 + mb * 16 + lk * 4;
#pragma unroll
    for (int nb = 0; nb < 2; ++nb) {
      int c = w * 32 + nb * 16 + lr;
#pragma unroll
      for (int j = 0; j < 4; ++j) {
        if (r + j < N) {
          unsigned short val = f2bf(acc[mb][nb][j]);
          if (c < 64) y2[(size_t)(r + j) * 64 + c] = val;
          else        r2[(size_t)(r + j) * 64 + (c - 64)] = val;
        }
      }
    }
  }
}

// ---------------- fused agg2 + h2 + classifier (wave per node) --------------
__global__ void k_agghead(const unsigned short* __restrict__ y2,
                          const unsigned short* __restrict__ r2,
                          const int* __restrict__ rowptr, const int* __restrict__ col,
                          const float* __restrict__ b2, const float* __restrict__ Wc,
                          const float* __restrict__ bc, float* __restrict__ out, int n) {
  int wid = (int)(((size_t)blockIdx.x * blockDim.x + threadIdx.x) >> 6);
  int l = threadIdx.x & 63;
  if (wid >= n) return;
  int rp0 = rowptr[wid], rp1 = rowptr[wid + 1];
  int g = l >> 3, s = l & 7;
  float acc[8];
#pragma unroll
  for (int q = 0; q < 8; ++q) acc[q] = 0.f;
  int j = rp0 + g;
  for (; j + 8 < rp1; j += 16) {
    int c0 = col[j], c1 = col[j + 8];
    bf16x8 v0 = *(const bf16x8*)&y2[(size_t)c0 * 64 + s * 8];
    bf16x8 v1 = *(const bf16x8*)&y2[(size_t)c1 * 64 + s * 8];
#pragma unroll
    for (int q = 0; q < 8; ++q)
      acc[q] += bf2f((unsigned short)v0[q]) + bf2f((unsigned short)v1[q]);
  }
  if (j < rp1) {
    int c0 = col[j];
    bf16x8 v0 = *(const bf16x8*)&y2[(size_t)c0 * 64 + s * 8];
#pragma unroll
    for (int q = 0; q < 8; ++q) acc[q] += bf2f((unsigned short)v0[q]);
  }
#pragma unroll
  for (int q = 0; q < 8; ++q) {
    acc[q] += __shfl_xor(acc[q], 8, 64);
    acc[q] += __shfl_xor(acc[q], 16, 64);
    acc[q] += __shfl_xor(acc[q], 32, 64);
  }
  if (g == 0) {
    int d = rp1 - rp0;
    float inv = 1.f / (float)(d > 1 ? d : 1);
    bf16x8 rr = *(const bf16x8*)&r2[(size_t)wid * 64 + s * 8];
    float4 bb0 = *(const float4*)&b2[s * 8];
    float4 bb1 = *(const float4*)&b2[s * 8 + 4];
    float bbv[8] = {bb0.x, bb0.y, bb0.z, bb0.w, bb1.x, bb1.y, bb1.z, bb1.w};
    float4 wc0 = *(const float4*)&Wc[s * 8];
    float4 wc1 = *(const float4*)&Wc[s * 8 + 4];
    float wcv[8] = {wc0.x, wc0.y, wc0.z, wc0.w, wc1.x, wc1.y, wc1.z, wc1.w};
    float p = 0.f;
#pragma unroll
    for (int q = 0; q < 8; ++q) {
      float h = acc[q] * inv + bf2f((unsigned short)rr[q]) + bbv[q];
      h = h > 0.f ? h : 0.f;
      p += h * wcv[q];
    }
    p += __shfl_xor(p, 1, 64);
    p += __shfl_xor(p, 2, 64);
    p += __shfl_xor(p, 4, 64);
    if (s == 0) out[wid] = p + bc[0];
  }
}

extern "C" void kernel_launch(void* const* d_in, const int* in_sizes, int n_in,
                              void* d_out, int out_size, void* d_ws, size_t ws_size,
                              hipStream_t stream) {
  const float* x   = (const float*)d_in[0];
  const int*   ei  = (const int*)d_in[1];
  const float* W1l = (const float*)d_in[2];
  const float* W1r = (const float*)d_in[3];
  const float* b1  = (const float*)d_in[4];
  const float* W2l = (const float*)d_in[5];
  const float* W2r = (const float*)d_in[6];
  const float* b2  = (const float*)d_in[7];
  const float* Wc  = (const float*)d_in[8];
  const float* bc  = (const float*)d_in[9];
  float* logits = (float*)d_out;

  const int N = in_sizes[0] / 128;  // 100000
  const int E = in_sizes[1] / 2;    // 1600000
  const int NB = (N + 127) >> 7;    // 782 buckets (128 nodes each)
  const int EC = (E + NWG - 1) / NWG;  // 3125 edges per chunk WG

  char* ws = (char*)d_ws;
  size_t o = 0;
  auto alloc = [&](size_t bytes) { size_t r = o; o += (bytes + 511) & ~511ULL; return r; };
  size_t o_rp    = alloc((size_t)(N + 1) * 4);
  size_t o_bcc   = alloc((size_t)(2 * NB) * 4);  // bcnt | bcur (one memset)
  size_t o_col   = alloc((size_t)E * 4);
  size_t o_ebuf  = alloc((size_t)E * 4);         // packed 4B edges
  size_t o_t1    = alloc((size_t)N * 128 * 2);   // bf16 gather table L1
  size_t o_r1    = alloc((size_t)N * 128 * 2);   // bf16 root transform L1
  size_t o_h1    = alloc((size_t)N * 128 * 2);   // bf16 h1
  size_t o_y2r2  = alloc((size_t)N * 128 * 2);   // y2 (N*64) | r2 (N*64) bf16
  if (o > ws_size) return;

  int* rp    = (int*)(ws + o_rp);
  int* bcnt  = (int*)(ws + o_bcc);
  int* bcur  = bcnt + NB;
  int* col   = (int*)(ws + o_col);
  int* ebuf  = (int*)(ws + o_ebuf);
  unsigned short* t1 = (unsigned short*)(ws + o_t1);
  unsigned short* r1 = (unsigned short*)(ws + o_r1);
  unsigned short* h1 = (unsigned short*)(ws + o_h1);
  unsigned short* y2 = (unsigned short*)(ws + o_y2r2);
  unsigned short* r2 = y2 + (size_t)N * 64;

  const int* esrc = ei;
  const int* edst = ei + E;

  int gtiles = (N + 63) / 64;                               // 1563
  int nodeblocks = (int)(((size_t)N * 64 + TPB - 1) / TPB); // 25000

  hipMemsetAsync(bcnt, 0, (size_t)(2 * NB) * 4, stream);
  k_lin1d_bcount<<<gtiles + NWG, TPB, 0, stream>>>(
      x, W1l, W1r, t1, r1, N, edst, bcnt, E, NB, EC, gtiles);
  k_bscatter<<<NWG, TPB, 0, stream>>>(esrc, edst, bcnt, bcur, ebuf, E, NB, EC);
  k_bcsr<<<NB, TPB, 0, stream>>>(ebuf, bcnt, rp, col, N, NB);
  k_aggh1<<<nodeblocks, TPB, 0, stream>>>(t1, r1, rp, col, b1, h1, N);
  k_lin2<<<gtiles, TPB, 0, stream>>>(h1, W2l, W2r, y2, r2, N);
  k_agghead<<<nodeblocks, TPB, 0, stream>>>(y2, r2, rp, col, b2, Wc, bc, logits, N);
}

// Round 9
// 227.006 us; speedup vs baseline: 1.0356x; 1.0356x over previous
//
#include <hip/hip_runtime.h>

// GraphSAGE 2-layer + classifier on MI355X (gfx950).
// fp8-e4m3 gather tables (halve fabric-floor traffic), bf16 MFMA GEMMs,
// lean bucket CSR build.
//
//   memset bcnt|bcur = 0
//   k_bcount: LDS histogram of dst>>7 -> bcnt (3.1KB LDS, high occupancy)
//   k_lin1d:  t1 = fp8(x @ W1l.T) [gather table], r1 = bf16(x @ W1r.T)
//   k_bscatter: per-WG scan of bcnt -> bases; stage chunk; reserve runs; emit
//   k_bcsr:   per 128-node bucket: degree count + scan -> rowptr, col
//   k_aggh1:  wave/node: h1 = bf16(relu(gather-sum_fp8(t1)/deg + r1 + b1))
//   k_lin2:   y2 = fp8(h1 @ W2l.T) [gather table], r2 = bf16(h1 @ W2r.T)
//   k_agghead: wave/node: logit = relu(gather-sum_fp8(y2)/deg + r2 + b2).Wc+bc

static constexpr int TPB = 256;
static constexpr int NWG = 512;    // edge-chunk workgroups
static constexpr int ECMAX = 3200; // >= E/NWG = 3125
static constexpr int NBMAX = 1024; // >= ceil(N/128) = 782

typedef __attribute__((ext_vector_type(8))) short bf16x8;
typedef __attribute__((ext_vector_type(4))) float f32x4;
typedef __attribute__((ext_vector_type(2))) float f32x2;

#if __has_builtin(__builtin_amdgcn_cvt_pk_f32_fp8) && __has_builtin(__builtin_amdgcn_cvt_pk_fp8_f32)
#define FP8_HW 1
#endif

__device__ __forceinline__ unsigned short f2bf(float f) {
  union { float f; unsigned u; } v; v.f = f;
  unsigned r = v.u + 0x7FFFu + ((v.u >> 16) & 1u);  // RNE
  return (unsigned short)(r >> 16);
}
__device__ __forceinline__ float bf2f(unsigned short h) {
  union { unsigned u; float f; } v; v.u = ((unsigned)h) << 16;
  return v.f;
}

// ---- fp8 e4m3fn helpers (HW cvt preferred; manual fallback) ----
__device__ __forceinline__ float fp82f_sw(unsigned u) {
  unsigned e = (u >> 3) & 15u, m = u & 7u;
  float f;
  if (e == 0) f = (float)m * 0.001953125f;  // m * 2^-9
  else {
    union { unsigned u; float f; } v;
    v.u = ((e + 120u) << 23) | (m << 20);
    f = v.f;
  }
  return (u & 0x80u) ? -f : f;
}

__device__ __forceinline__ unsigned char f2fp8(float f) {
#ifdef FP8_HW
  return (unsigned char)(__builtin_amdgcn_cvt_pk_fp8_f32(f, f, 0, false) & 0xFF);
#else
  union { float f; unsigned u; } v; v.f = f;
  unsigned s = (v.u >> 24) & 0x80u;
  unsigned a = v.u & 0x7FFFFFFFu;
  if (a >= 0x43E00000u) return (unsigned char)(s | 0x7Eu);  // clamp to 448
  int e32 = (int)(a >> 23);
  if (e32 < 121) {  // subnormal region (< 2^-6)
    float sc = __builtin_fabsf(f) * 512.0f;  // 2^9
    int m = (int)(sc + 0.5f);
    if (m >= 8) return (unsigned char)(s | 0x08u);
    return (unsigned char)(s | (unsigned)m);
  }
  unsigned m = a & 0x7FFFFFu;
  unsigned lsb = (m >> 20) & 1u;
  m += 0x7FFFFu + lsb;
  unsigned e8 = (unsigned)(e32 - 120);
  if (m >= 0x800000u) { m -= 0x800000u; e8 += 1; }
  if (e8 >= 16) return (unsigned char)(s | 0x7Eu);
  return (unsigned char)(s | (e8 << 3) | (m >> 20));
#endif
}

// accumulate 8 fp8 (as uint2) into acc[8]
__device__ __forceinline__ void fp8x8_acc(uint2 v, float* acc) {
#ifdef FP8_HW
  f32x2 a0 = __builtin_amdgcn_cvt_pk_f32_fp8(v.x, false);
  f32x2 a1 = __builtin_amdgcn_cvt_pk_f32_fp8(v.x, true);
  f32x2 a2 = __builtin_amdgcn_cvt_pk_f32_fp8(v.y, false);
  f32x2 a3 = __builtin_amdgcn_cvt_pk_f32_fp8(v.y, true);
  acc[0] += a0[0]; acc[1] += a0[1]; acc[2] += a1[0]; acc[3] += a1[1];
  acc[4] += a2[0]; acc[5] += a2[1]; acc[6] += a3[0]; acc[7] += a3[1];
#else
  acc[0] += fp82f_sw(v.x & 255); acc[1] += fp82f_sw((v.x >> 8) & 255);
  acc[2] += fp82f_sw((v.x >> 16) & 255); acc[3] += fp82f_sw(v.x >> 24);
  acc[4] += fp82f_sw(v.y & 255); acc[5] += fp82f_sw((v.y >> 8) & 255);
  acc[6] += fp82f_sw((v.y >> 16) & 255); acc[7] += fp82f_sw(v.y >> 24);
#endif
}

// ---------------- bucket CSR build (no per-edge global atomics) -------------
__global__ __launch_bounds__(TPB) void k_bcount(const int* __restrict__ dst,
                                                int* __restrict__ bcnt,
                                                int E, int NB, int EC) {
  extern __shared__ int lhist0[];  // NB ints (~3.1KB)
  int t = threadIdx.x;
  for (int b = t; b < NB; b += TPB) lhist0[b] = 0;
  __syncthreads();
  int base = blockIdx.x * EC;
  int cnt = min(EC, E - base);
  for (int i = t; i < cnt; i += TPB)
    atomicAdd(&lhist0[dst[base + i] >> 7], 1);
  __syncthreads();
  for (int b = t; b < NB; b += TPB) {
    int c = lhist0[b];
    if (c) atomicAdd(&bcnt[b], c);
  }
}

__global__ __launch_bounds__(TPB) void k_bscatter(
    const int* __restrict__ src, const int* __restrict__ dst,
    const int* __restrict__ bcnt, int* __restrict__ bcur,
    int* __restrict__ ebuf, int E, int NB, int EC) {
  __shared__ int pv[ECMAX];
  __shared__ unsigned short kb[ECMAX];
  __shared__ int sb[NBMAX];     // exclusive scan of bcnt (bucket bases)
  __shared__ int lhist[NBMAX];
  __shared__ int lcur[NBMAX];
  __shared__ int sp[TPB];
  int t = threadIdx.x;
  int loc[4]; int ssum = 0;
#pragma unroll
  for (int q = 0; q < 4; ++q) {
    int idx = t * 4 + q;
    loc[q] = (idx < NB) ? bcnt[idx] : 0;
    ssum += loc[q];
  }
  sp[t] = ssum; __syncthreads();
  for (int off = 1; off < TPB; off <<= 1) {
    int x = (t >= off) ? sp[t - off] : 0;
    __syncthreads();
    sp[t] += x;
    __syncthreads();
  }
  int run = sp[t] - ssum;
#pragma unroll
  for (int q = 0; q < 4; ++q) {
    int idx = t * 4 + q;
    if (idx < NB) sb[idx] = run;
    run += loc[q];
  }
  for (int b = t; b < NB; b += TPB) lhist[b] = 0;
  int base = blockIdx.x * EC;
  int cnt = min(EC, E - base);
  __syncthreads();
  for (int i = t; i < cnt; i += TPB) {
    int sv = src[base + i], dv = dst[base + i];
    int b = dv >> 7;
    kb[i] = (unsigned short)b;
    pv[i] = ((dv & 127) << 17) | sv;
    atomicAdd(&lhist[b], 1);
  }
  __syncthreads();
  for (int b = t; b < NB; b += TPB) {
    int c = lhist[b];
    lcur[b] = c ? (sb[b] + atomicAdd(&bcur[b], c)) : 0;
  }
  __syncthreads();
  for (int i = t; i < cnt; i += TPB) {
    int b = kb[i];
    int pos = atomicAdd(&lcur[b], 1);
    ebuf[pos] = pv[i];
  }
}

__global__ __launch_bounds__(TPB) void k_bcsr(
    const int* __restrict__ ebuf, const int* __restrict__ bcnt,
    int* __restrict__ rowptr, int* __restrict__ col, int N, int NB) {
  __shared__ int deg[128], sscan[128], lcur[128], red[TPB];
  int b = blockIdx.x, t = threadIdx.x;
  int part = 0;
  for (int i = t; i < b; i += TPB) part += bcnt[i];
  red[t] = part; __syncthreads();
  for (int off = TPB / 2; off > 0; off >>= 1) {
    if (t < off) red[t] += red[t + off];
    __syncthreads();
  }
  int e0 = red[0];
  int e1 = e0 + bcnt[b];
  if (t < 128) deg[t] = 0;
  __syncthreads();
  for (int i = e0 + t; i < e1; i += TPB)
    atomicAdd(&deg[ebuf[i] >> 17], 1);
  __syncthreads();
  if (t < 128) sscan[t] = deg[t];
  __syncthreads();
  for (int off = 1; off < 128; off <<= 1) {
    int x = 0;
    if (t < 128 && t >= off) x = sscan[t - off];
    __syncthreads();
    if (t < 128) sscan[t] += x;
    __syncthreads();
  }
  if (t < 128) {
    int excl = sscan[t] - deg[t];
    int node0 = (b << 7) + t;
    if (node0 < N) rowptr[node0] = e0 + excl;
    lcur[t] = e0 + excl;
  }
  if (b == NB - 1 && t == 0) rowptr[N] = e1;
  __syncthreads();
  for (int i = e0 + t; i < e1; i += TPB) {
    int pvv = ebuf[i];
    int pos = atomicAdd(&lcur[pvv >> 17], 1);
    col[pos] = pvv & 0x1FFFF;
  }
}

// ---------------- bf16 MFMA GEMM pieces ----------------
static constexpr int LD = 136;  // padded bf16 leading dim (2-way aliasing = free)

// OUT8: write fp8 bytes (stride 128B rows); else bf16 (stride 128 elems)
template <bool OUT8>
__device__ __forceinline__ void mfma_tile_128(
    const unsigned short* As, const unsigned short* Bs,
    void* __restrict__ outp, int row0, int N, int w, int l) {
  int lr = l & 15, lk = l >> 4;
  f32x4 acc[4][2];
#pragma unroll
  for (int mb = 0; mb < 4; ++mb)
#pragma unroll
    for (int nb = 0; nb < 2; ++nb)
#pragma unroll
      for (int q = 0; q < 4; ++q) acc[mb][nb][q] = 0.f;
#pragma unroll
  for (int ks = 0; ks < 4; ++ks) {
    int koff = ks * 32 + lk * 8;
    bf16x8 a[4], bfr[2];
#pragma unroll
    for (int mb = 0; mb < 4; ++mb)
      a[mb] = *(const bf16x8*)&As[(mb * 16 + lr) * LD + koff];
#pragma unroll
    for (int nb = 0; nb < 2; ++nb)
      bfr[nb] = *(const bf16x8*)&Bs[(w * 32 + nb * 16 + lr) * LD + koff];
#pragma unroll
    for (int mb = 0; mb < 4; ++mb)
#pragma unroll
      for (int nb = 0; nb < 2; ++nb)
        acc[mb][nb] = __builtin_amdgcn_mfma_f32_16x16x32_bf16(a[mb], bfr[nb], acc[mb][nb], 0, 0, 0);
  }
#pragma unroll
  for (int mb = 0; mb < 4; ++mb) {
    int r = row0 + mb * 16 + lk * 4;
#pragma unroll
    for (int nb = 0; nb < 2; ++nb) {
      int c = w * 32 + nb * 16 + lr;
#pragma unroll
      for (int j = 0; j < 4; ++j) {
        if (r + j < N) {
          if (OUT8) ((unsigned char*)outp)[(size_t)(r + j) * 128 + c] = f2fp8(acc[mb][nb][j]);
          else      ((unsigned short*)outp)[(size_t)(r + j) * 128 + c] = f2bf(acc[mb][nb][j]);
        }
      }
    }
  }
}

// layer-1 dual GEMM: t1 = fp8(x@W1l.T), r1 = bf16(x@W1r.T); x staged once
__global__ __launch_bounds__(TPB) void k_lin1d(
    const float* __restrict__ X, const float* __restrict__ W1l,
    const float* __restrict__ W1r, unsigned char* __restrict__ t1,
    unsigned short* __restrict__ r1, int N) {
  __shared__ unsigned short Bs[128 * LD];
  __shared__ unsigned short As[64 * LD];
  int t = threadIdx.x;
  int row0 = blockIdx.x * 64;
  for (int i = t; i < 64 * 32; i += TPB) {
    int r = i >> 5, k4 = i & 31;
    int gr = row0 + r;
    float4 v;
    if (gr < N) v = *(const float4*)&X[(size_t)gr * 128 + k4 * 4];
    else { v.x = v.y = v.z = v.w = 0.f; }
    ushort4 o; o.x = f2bf(v.x); o.y = f2bf(v.y); o.z = f2bf(v.z); o.w = f2bf(v.w);
    *(ushort4*)&As[r * LD + k4 * 4] = o;
  }
  for (int i = t; i < 128 * 32; i += TPB) {
    int r = i >> 5, k4 = i & 31;
    float4 v = *(const float4*)&W1l[r * 128 + k4 * 4];
    ushort4 o; o.x = f2bf(v.x); o.y = f2bf(v.y); o.z = f2bf(v.z); o.w = f2bf(v.w);
    *(ushort4*)&Bs[r * LD + k4 * 4] = o;
  }
  __syncthreads();
  int w = t >> 6, l = t & 63;
  mfma_tile_128<true>(As, Bs, t1, row0, N, w, l);
  __syncthreads();
  for (int i = t; i < 128 * 32; i += TPB) {
    int r = i >> 5, k4 = i & 31;
    float4 v = *(const float4*)&W1r[r * 128 + k4 * 4];
    ushort4 o; o.x = f2bf(v.x); o.y = f2bf(v.y); o.z = f2bf(v.z); o.w = f2bf(v.w);
    *(ushort4*)&Bs[r * LD + k4 * 4] = o;
  }
  __syncthreads();
  mfma_tile_128<false>(As, Bs, r1, row0, N, w, l);
}

// ---------------- gather(fp8) + h1 (wave per node, 4-deep unroll) -----------
__global__ void k_aggh1(const unsigned char* __restrict__ t1,
                        const unsigned short* __restrict__ r1,
                        const int* __restrict__ rowptr, const int* __restrict__ col,
                        const float* __restrict__ b1,
                        unsigned short* __restrict__ h1, int n) {
  int wid = (int)(((size_t)blockIdx.x * blockDim.x + threadIdx.x) >> 6);
  int l = threadIdx.x & 63;
  if (wid >= n) return;
  int rp0 = rowptr[wid], rp1 = rowptr[wid + 1];
  int g = l >> 4, s = l & 15;
  float acc[8];
#pragma unroll
  for (int q = 0; q < 8; ++q) acc[q] = 0.f;
  int j = rp0 + g;
  for (; j + 12 < rp1; j += 16) {
    int c0 = col[j], c1 = col[j + 4], c2 = col[j + 8], c3 = col[j + 12];
    uint2 v0 = *(const uint2*)&t1[(size_t)c0 * 128 + s * 8];
    uint2 v1 = *(const uint2*)&t1[(size_t)c1 * 128 + s * 8];
    uint2 v2 = *(const uint2*)&t1[(size_t)c2 * 128 + s * 8];
    uint2 v3 = *(const uint2*)&t1[(size_t)c3 * 128 + s * 8];
    fp8x8_acc(v0, acc); fp8x8_acc(v1, acc);
    fp8x8_acc(v2, acc); fp8x8_acc(v3, acc);
  }
  for (; j + 4 < rp1; j += 8) {
    int c0 = col[j], c1 = col[j + 4];
    uint2 v0 = *(const uint2*)&t1[(size_t)c0 * 128 + s * 8];
    uint2 v1 = *(const uint2*)&t1[(size_t)c1 * 128 + s * 8];
    fp8x8_acc(v0, acc); fp8x8_acc(v1, acc);
  }
  if (j < rp1) {
    uint2 v0 = *(const uint2*)&t1[(size_t)col[j] * 128 + s * 8];
    fp8x8_acc(v0, acc);
  }
#pragma unroll
  for (int q = 0; q < 8; ++q) {
    acc[q] += __shfl_xor(acc[q], 16, 64);
    acc[q] += __shfl_xor(acc[q], 32, 64);
  }
  if (g == 0) {
    int d = rp1 - rp0;
    float inv = 1.f / (float)(d > 1 ? d : 1);
    bf16x8 rr = *(const bf16x8*)&r1[(size_t)wid * 128 + s * 8];
    float4 bb0 = *(const float4*)&b1[s * 8];
    float4 bb1 = *(const float4*)&b1[s * 8 + 4];
    float bbv[8] = {bb0.x, bb0.y, bb0.z, bb0.w, bb1.x, bb1.y, bb1.z, bb1.w};
    bf16x8 o;
#pragma unroll
    for (int q = 0; q < 8; ++q) {
      float h = acc[q] * inv + bf2f((unsigned short)rr[q]) + bbv[q];
      h = h > 0.f ? h : 0.f;
      o[q] = (short)f2bf(h);
    }
    *(bf16x8*)&h1[(size_t)wid * 128 + s * 8] = o;
  }
}

// layer-2 GEMM: y2 = fp8(h1 @ W2l.T) [64B rows], r2 = bf16(h1 @ W2r.T)
__global__ __launch_bounds__(TPB) void k_lin2(
    const unsigned short* __restrict__ h1,
    const float* __restrict__ W2l, const float* __restrict__ W2r,
    unsigned char* __restrict__ y2, unsigned short* __restrict__ r2, int N) {
  __shared__ unsigned short Bs[128 * LD];
  __shared__ unsigned short As[64 * LD];
  int t = threadIdx.x;
  for (int i = t; i < 128 * 32; i += TPB) {  // B rows 0-63: W2l, 64-127: W2r
    int r = i >> 5, k4 = i & 31;
    const float* srcp = (r < 64) ? &W2l[(size_t)r * 128 + k4 * 4]
                                 : &W2r[(size_t)(r - 64) * 128 + k4 * 4];
    float4 v = *(const float4*)srcp;
    ushort4 o; o.x = f2bf(v.x); o.y = f2bf(v.y); o.z = f2bf(v.z); o.w = f2bf(v.w);
    *(ushort4*)&Bs[r * LD + k4 * 4] = o;
  }
  int row0 = blockIdx.x * 64;
  for (int i = t * 8; i < 64 * 128; i += TPB * 8) {
    int r = i >> 7, k8 = i & 127;
    int gr = row0 + r;
    bf16x8 v;
    if (gr < N) v = *(const bf16x8*)&h1[(size_t)gr * 128 + k8];
    else { for (int q = 0; q < 8; ++q) v[q] = 0; }
    *(bf16x8*)&As[r * LD + k8] = v;
  }
  __syncthreads();
  int w = t >> 6, l = t & 63;
  int lr = l & 15, lk = l >> 4;
  f32x4 acc[4][2];
#pragma unroll
  for (int mb = 0; mb < 4; ++mb)
#pragma unroll
    for (int nb = 0; nb < 2; ++nb)
#pragma unroll
      for (int q = 0; q < 4; ++q) acc[mb][nb][q] = 0.f;
#pragma unroll
  for (int ks = 0; ks < 4; ++ks) {
    int koff = ks * 32 + lk * 8;
    bf16x8 a[4], bfr[2];
#pragma unroll
    for (int mb = 0; mb < 4; ++mb)
      a[mb] = *(const bf16x8*)&As[(mb * 16 + lr) * LD + koff];
#pragma unroll
    for (int nb = 0; nb < 2; ++nb)
      bfr[nb] = *(const bf16x8*)&Bs[(w * 32 + nb * 16 + lr) * LD + koff];
#pragma unroll
    for (int mb = 0; mb < 4; ++mb)
#pragma unroll
      for (int nb = 0; nb < 2; ++nb)
        acc[mb][nb] = __builtin_amdgcn_mfma_f32_16x16x32_bf16(a[mb], bfr[nb], acc[mb][nb], 0, 0, 0);
  }
#pragma unroll
  for (int mb = 0; mb < 4; ++mb) {
    int r = row0 + mb * 16 + lk * 4;
#pragma unroll
    for (int nb = 0; nb < 2; ++nb) {
      int c = w * 32 + nb * 16 + lr;
#pragma unroll
      for (int j = 0; j < 4; ++j) {
        if (r + j < N) {
          if (c < 64) y2[(size_t)(r + j) * 64 + c] = f2fp8(acc[mb][nb][j]);
          else        r2[(size_t)(r + j) * 64 + (c - 64)] = f2bf(acc[mb][nb][j]);
        }
      }
    }
  }
}

// ---------------- gather(fp8) + h2 + classifier (wave per node) -------------
__global__ void k_agghead(const unsigned char* __restrict__ y2,
                          const unsigned short* __restrict__ r2,
                          const int* __restrict__ rowptr, const int* __restrict__ col,
                          const float* __restrict__ b2, const float* __restrict__ Wc,
                          const float* __restrict__ bc, float* __restrict__ out, int n) {
  int wid = (int)(((size_t)blockIdx.x * blockDim.x + threadIdx.x) >> 6);
  int l = threadIdx.x & 63;
  if (wid >= n) return;
  int rp0 = rowptr[wid], rp1 = rowptr[wid + 1];
  int g = l >> 3, s = l & 7;
  float acc[8];
#pragma unroll
  for (int q = 0; q < 8; ++q) acc[q] = 0.f;
  int j = rp0 + g;
  for (; j + 8 < rp1; j += 16) {
    int c0 = col[j], c1 = col[j + 8];
    uint2 v0 = *(const uint2*)&y2[(size_t)c0 * 64 + s * 8];
    uint2 v1 = *(const uint2*)&y2[(size_t)c1 * 64 + s * 8];
    fp8x8_acc(v0, acc); fp8x8_acc(v1, acc);
  }
  if (j < rp1) {
    uint2 v0 = *(const uint2*)&y2[(size_t)col[j] * 64 + s * 8];
    fp8x8_acc(v0, acc);
  }
#pragma unroll
  for (int q = 0; q < 8; ++q) {
    acc[q] += __shfl_xor(acc[q], 8, 64);
    acc[q] += __shfl_xor(acc[q], 16, 64);
    acc[q] += __shfl_xor(acc[q], 32, 64);
  }
  if (g == 0) {
    int d = rp1 - rp0;
    float inv = 1.f / (float)(d > 1 ? d : 1);
    bf16x8 rr = *(const bf16x8*)&r2[(size_t)wid * 64 + s * 8];
    float4 bb0 = *(const float4*)&b2[s * 8];
    float4 bb1 = *(const float4*)&b2[s * 8 + 4];
    float bbv[8] = {bb0.x, bb0.y, bb0.z, bb0.w, bb1.x, bb1.y, bb1.z, bb1.w};
    float4 wc0 = *(const float4*)&Wc[s * 8];
    float4 wc1 = *(const float4*)&Wc[s * 8 + 4];
    float wcv[8] = {wc0.x, wc0.y, wc0.z, wc0.w, wc1.x, wc1.y, wc1.z, wc1.w};
    float p = 0.f;
#pragma unroll
    for (int q = 0; q < 8; ++q) {
      float h = acc[q] * inv + bf2f((unsigned short)rr[q]) + bbv[q];
      h = h > 0.f ? h : 0.f;
      p += h * wcv[q];
    }
    p += __shfl_xor(p, 1, 64);
    p += __shfl_xor(p, 2, 64);
    p += __shfl_xor(p, 4, 64);
    if (s == 0) out[wid] = p + bc[0];
  }
}

extern "C" void kernel_launch(void* const* d_in, const int* in_sizes, int n_in,
                              void* d_out, int out_size, void* d_ws, size_t ws_size,
                              hipStream_t stream) {
  const float* x   = (const float*)d_in[0];
  const int*   ei  = (const int*)d_in[1];
  const float* W1l = (const float*)d_in[2];
  const float* W1r = (const float*)d_in[3];
  const float* b1  = (const float*)d_in[4];
  const float* W2l = (const float*)d_in[5];
  const float* W2r = (const float*)d_in[6];
  const float* b2  = (const float*)d_in[7];
  const float* Wc  = (const float*)d_in[8];
  const float* bc  = (const float*)d_in[9];
  float* logits = (float*)d_out;

  const int N = in_sizes[0] / 128;  // 100000
  const int E = in_sizes[1] / 2;    // 1600000
  const int NB = (N + 127) >> 7;    // 782 buckets (128 nodes each)
  const int EC = (E + NWG - 1) / NWG;  // 3125 edges per chunk WG

  char* ws = (char*)d_ws;
  size_t o = 0;
  auto alloc = [&](size_t bytes) { size_t r = o; o += (bytes + 511) & ~511ULL; return r; };
  size_t o_rp    = alloc((size_t)(N + 1) * 4);
  size_t o_bcc   = alloc((size_t)(2 * NB) * 4);  // bcnt | bcur (one memset)
  size_t o_col   = alloc((size_t)E * 4);
  size_t o_ebuf  = alloc((size_t)E * 4);         // packed 4B edges
  size_t o_t1    = alloc((size_t)N * 128);       // fp8 gather table L1 (12.8MB)
  size_t o_r1    = alloc((size_t)N * 128 * 2);   // bf16 root transform L1
  size_t o_h1    = alloc((size_t)N * 128 * 2);   // bf16 h1
  size_t o_y2    = alloc((size_t)N * 64);        // fp8 gather table L2 (6.4MB)
  size_t o_r2    = alloc((size_t)N * 64 * 2);    // bf16 root transform L2
  if (o > ws_size) return;

  int* rp    = (int*)(ws + o_rp);
  int* bcnt  = (int*)(ws + o_bcc);
  int* bcur  = bcnt + NB;
  int* col   = (int*)(ws + o_col);
  int* ebuf  = (int*)(ws + o_ebuf);
  unsigned char*  t1 = (unsigned char*)(ws + o_t1);
  unsigned short* r1 = (unsigned short*)(ws + o_r1);
  unsigned short* h1 = (unsigned short*)(ws + o_h1);
  unsigned char*  y2 = (unsigned char*)(ws + o_y2);
  unsigned short* r2 = (unsigned short*)(ws + o_r2);

  const int* esrc = ei;
  const int* edst = ei + E;

  int gtiles = (N + 63) / 64;                               // 1563
  int nodeblocks = (int)(((size_t)N * 64 + TPB - 1) / TPB); // 25000

  hipMemsetAsync(bcnt, 0, (size_t)(2 * NB) * 4, stream);
  k_bcount<<<NWG, TPB, (size_t)NB * 4, stream>>>(edst, bcnt, E, NB, EC);
  k_lin1d<<<gtiles, TPB, 0, stream>>>(x, W1l, W1r, t1, r1, N);
  k_bscatter<<<NWG, TPB, 0, stream>>>(esrc, edst, bcnt, bcur, ebuf, E, NB, EC);
  k_bcsr<<<NB, TPB, 0, stream>>>(ebuf, bcnt, rp, col, N, NB);
  k_aggh1<<<nodeblocks, TPB, 0, stream>>>(t1, r1, rp, col, b1, h1, N);
  k_lin2<<<gtiles, TPB, 0, stream>>>(h1, W2l, W2r, y2, r2, N);
  k_agghead<<<nodeblocks, TPB, 0, stream>>>(y2, r2, rp, col, b2, Wc, bc, logits, N);
}

// Round 10
// 213.592 us; speedup vs baseline: 1.1007x; 1.0628x over previous
//
#include <hip/hip_runtime.h>

// GraphSAGE 2-layer + classifier on MI355X (gfx950).
// fp8-e4m3 gather tables, bf16 MFMA GEMMs with global-resident bf16 weights
// (no B-staging in LDS), lean bucket CSR build.
//
//   k_wprep:  W1l,W1r,W2l,W2r -> bf16 (98KB, L2-resident, shared by all blocks)
//   memset bcnt|bcur = 0
//   k_bcount: LDS histogram of dst>>7 -> bcnt
//   k_lin1:   t1 = fp8(x @ W1l.T), r1 = bf16(x @ W1r.T)  single pass, dual acc
//   k_bscatter: per-WG scan of bcnt -> bases; stage chunk; reserve runs; emit
//   k_bcsr:   per 128-node bucket: degree count + scan -> rowptr, col
//   k_aggh1:  wave/node: h1 = bf16(relu(gather-sum_fp8(t1)/deg + r1 + b1))
//   k_lin2:   y2 = fp8(h1 @ W2l.T), r2 = bf16(h1 @ W2r.T)
//   k_agghead: wave/node: logit = relu(gather-sum_fp8(y2)/deg + r2 + b2).Wc+bc

static constexpr int TPB = 256;
static constexpr int NWG = 512;    // edge-chunk workgroups
static constexpr int ECMAX = 3200; // >= E/NWG = 3125
static constexpr int NBMAX = 1024; // >= ceil(N/128) = 782

typedef __attribute__((ext_vector_type(8))) short bf16x8;
typedef __attribute__((ext_vector_type(4))) float f32x4;
typedef __attribute__((ext_vector_type(2))) float f32x2;

#if __has_builtin(__builtin_amdgcn_cvt_pk_f32_fp8) && __has_builtin(__builtin_amdgcn_cvt_pk_fp8_f32)
#define FP8_HW 1
#endif

__device__ __forceinline__ unsigned short f2bf(float f) {
  union { float f; unsigned u; } v; v.f = f;
  unsigned r = v.u + 0x7FFFu + ((v.u >> 16) & 1u);  // RNE
  return (unsigned short)(r >> 16);
}
__device__ __forceinline__ float bf2f(unsigned short h) {
  union { unsigned u; float f; } v; v.u = ((unsigned)h) << 16;
  return v.f;
}

// ---- fp8 e4m3fn helpers (HW cvt preferred; manual fallback) ----
__device__ __forceinline__ float fp82f_sw(unsigned u) {
  unsigned e = (u >> 3) & 15u, m = u & 7u;
  float f;
  if (e == 0) f = (float)m * 0.001953125f;  // m * 2^-9
  else {
    union { unsigned u; float f; } v;
    v.u = ((e + 120u) << 23) | (m << 20);
    f = v.f;
  }
  return (u & 0x80u) ? -f : f;
}

__device__ __forceinline__ unsigned char f2fp8(float f) {
#ifdef FP8_HW
  return (unsigned char)(__builtin_amdgcn_cvt_pk_fp8_f32(f, f, 0, false) & 0xFF);
#else
  union { float f; unsigned u; } v; v.f = f;
  unsigned s = (v.u >> 24) & 0x80u;
  unsigned a = v.u & 0x7FFFFFFFu;
  if (a >= 0x43E00000u) return (unsigned char)(s | 0x7Eu);  // clamp to 448
  int e32 = (int)(a >> 23);
  if (e32 < 121) {  // subnormal region (< 2^-6)
    float sc = __builtin_fabsf(f) * 512.0f;  // 2^9
    int m = (int)(sc + 0.5f);
    if (m >= 8) return (unsigned char)(s | 0x08u);
    return (unsigned char)(s | (unsigned)m);
  }
  unsigned m = a & 0x7FFFFFu;
  unsigned lsb = (m >> 20) & 1u;
  m += 0x7FFFFu + lsb;
  unsigned e8 = (unsigned)(e32 - 120);
  if (m >= 0x800000u) { m -= 0x800000u; e8 += 1; }
  if (e8 >= 16) return (unsigned char)(s | 0x7Eu);
  return (unsigned char)(s | (e8 << 3) | (m >> 20));
#endif
}

// accumulate 8 fp8 (as uint2) into acc[8]
__device__ __forceinline__ void fp8x8_acc(uint2 v, float* acc) {
#ifdef FP8_HW
  f32x2 a0 = __builtin_amdgcn_cvt_pk_f32_fp8(v.x, false);
  f32x2 a1 = __builtin_amdgcn_cvt_pk_f32_fp8(v.x, true);
  f32x2 a2 = __builtin_amdgcn_cvt_pk_f32_fp8(v.y, false);
  f32x2 a3 = __builtin_amdgcn_cvt_pk_f32_fp8(v.y, true);
  acc[0] += a0[0]; acc[1] += a0[1]; acc[2] += a1[0]; acc[3] += a1[1];
  acc[4] += a2[0]; acc[5] += a2[1]; acc[6] += a3[0]; acc[7] += a3[1];
#else
  acc[0] += fp82f_sw(v.x & 255); acc[1] += fp82f_sw((v.x >> 8) & 255);
  acc[2] += fp82f_sw((v.x >> 16) & 255); acc[3] += fp82f_sw(v.x >> 24);
  acc[4] += fp82f_sw(v.y & 255); acc[5] += fp82f_sw((v.y >> 8) & 255);
  acc[6] += fp82f_sw((v.y >> 16) & 255); acc[7] += fp82f_sw(v.y >> 24);
#endif
}

// ---------------- weight prep: f32 -> bf16 (once, tiny) ----------------
__global__ void k_wprep(const float* __restrict__ W1l, const float* __restrict__ W1r,
                        const float* __restrict__ W2l, const float* __restrict__ W2r,
                        unsigned short* __restrict__ wb1l,
                        unsigned short* __restrict__ wb1r,
                        unsigned short* __restrict__ wb2) {
  int i = blockIdx.x * blockDim.x + threadIdx.x;
  if (i < 16384) wb1l[i] = f2bf(W1l[i]);
  else if (i < 32768) wb1r[i - 16384] = f2bf(W1r[i - 16384]);
  else if (i < 40960) wb2[i - 32768] = f2bf(W2l[i - 32768]);       // rows 0-63
  else if (i < 49152) wb2[8192 + i - 40960] = f2bf(W2r[i - 40960]); // rows 64-127
}

// ---------------- bucket CSR build (no per-edge global atomics) -------------
__global__ __launch_bounds__(TPB) void k_bcount(const int* __restrict__ dst,
                                                int* __restrict__ bcnt,
                                                int E, int NB, int EC) {
  extern __shared__ int lhist0[];  // NB ints (~3.1KB)
  int t = threadIdx.x;
  for (int b = t; b < NB; b += TPB) lhist0[b] = 0;
  __syncthreads();
  int base = blockIdx.x * EC;
  int cnt = min(EC, E - base);
  for (int i = t; i < cnt; i += TPB)
    atomicAdd(&lhist0[dst[base + i] >> 7], 1);
  __syncthreads();
  for (int b = t; b < NB; b += TPB) {
    int c = lhist0[b];
    if (c) atomicAdd(&bcnt[b], c);
  }
}

__global__ __launch_bounds__(TPB) void k_bscatter(
    const int* __restrict__ src, const int* __restrict__ dst,
    const int* __restrict__ bcnt, int* __restrict__ bcur,
    int* __restrict__ ebuf, int E, int NB, int EC) {
  __shared__ int pv[ECMAX];
  __shared__ unsigned short kb[ECMAX];
  __shared__ int sb[NBMAX];     // exclusive scan of bcnt (bucket bases)
  __shared__ int lhist[NBMAX];
  __shared__ int lcur[NBMAX];
  __shared__ int sp[TPB];
  int t = threadIdx.x;
  int loc[4]; int ssum = 0;
#pragma unroll
  for (int q = 0; q < 4; ++q) {
    int idx = t * 4 + q;
    loc[q] = (idx < NB) ? bcnt[idx] : 0;
    ssum += loc[q];
  }
  sp[t] = ssum; __syncthreads();
  for (int off = 1; off < TPB; off <<= 1) {
    int x = (t >= off) ? sp[t - off] : 0;
    __syncthreads();
    sp[t] += x;
    __syncthreads();
  }
  int run = sp[t] - ssum;
#pragma unroll
  for (int q = 0; q < 4; ++q) {
    int idx = t * 4 + q;
    if (idx < NB) sb[idx] = run;
    run += loc[q];
  }
  for (int b = t; b < NB; b += TPB) lhist[b] = 0;
  int base = blockIdx.x * EC;
  int cnt = min(EC, E - base);
  __syncthreads();
  for (int i = t; i < cnt; i += TPB) {
    int sv = src[base + i], dv = dst[base + i];
    int b = dv >> 7;
    kb[i] = (unsigned short)b;
    pv[i] = ((dv & 127) << 17) | sv;
    atomicAdd(&lhist[b], 1);
  }
  __syncthreads();
  for (int b = t; b < NB; b += TPB) {
    int c = lhist[b];
    lcur[b] = c ? (sb[b] + atomicAdd(&bcur[b], c)) : 0;
  }
  __syncthreads();
  for (int i = t; i < cnt; i += TPB) {
    int b = kb[i];
    int pos = atomicAdd(&lcur[b], 1);
    ebuf[pos] = pv[i];
  }
}

__global__ __launch_bounds__(TPB) void k_bcsr(
    const int* __restrict__ ebuf, const int* __restrict__ bcnt,
    int* __restrict__ rowptr, int* __restrict__ col, int N, int NB) {
  __shared__ int deg[128], sscan[128], lcur[128], red[TPB];
  int b = blockIdx.x, t = threadIdx.x;
  int part = 0;
  for (int i = t; i < b; i += TPB) part += bcnt[i];
  red[t] = part; __syncthreads();
  for (int off = TPB / 2; off > 0; off >>= 1) {
    if (t < off) red[t] += red[t + off];
    __syncthreads();
  }
  int e0 = red[0];
  int e1 = e0 + bcnt[b];
  if (t < 128) deg[t] = 0;
  __syncthreads();
  for (int i = e0 + t; i < e1; i += TPB)
    atomicAdd(&deg[ebuf[i] >> 17], 1);
  __syncthreads();
  if (t < 128) sscan[t] = deg[t];
  __syncthreads();
  for (int off = 1; off < 128; off <<= 1) {
    int x = 0;
    if (t < 128 && t >= off) x = sscan[t - off];
    __syncthreads();
    if (t < 128) sscan[t] += x;
    __syncthreads();
  }
  if (t < 128) {
    int excl = sscan[t] - deg[t];
    int node0 = (b << 7) + t;
    if (node0 < N) rowptr[node0] = e0 + excl;
    lcur[t] = e0 + excl;
  }
  if (b == NB - 1 && t == 0) rowptr[N] = e1;
  __syncthreads();
  for (int i = e0 + t; i < e1; i += TPB) {
    int pvv = ebuf[i];
    int pos = atomicAdd(&lcur[pvv >> 17], 1);
    col[pos] = pvv & 0x1FFFF;
  }
}

// ---------------- MFMA GEMMs: A in LDS, B direct from global bf16 -----------
static constexpr int LD = 136;  // padded bf16 leading dim (2-way aliasing = free)

// layer-1: single pass, dual accumulators (t1 fp8 + r1 bf16), B from global
__global__ __launch_bounds__(TPB, 4) void k_lin1(
    const float* __restrict__ X, const unsigned short* __restrict__ wl,
    const unsigned short* __restrict__ wr, unsigned char* __restrict__ t1,
    unsigned short* __restrict__ r1, int N) {
  __shared__ unsigned short As[64 * LD];
  int t = threadIdx.x;
  int row0 = blockIdx.x * 64;
  for (int i = t; i < 64 * 32; i += TPB) {
    int r = i >> 5, k4 = i & 31;
    int gr = row0 + r;
    float4 v;
    if (gr < N) v = *(const float4*)&X[(size_t)gr * 128 + k4 * 4];
    else { v.x = v.y = v.z = v.w = 0.f; }
    ushort4 o; o.x = f2bf(v.x); o.y = f2bf(v.y); o.z = f2bf(v.z); o.w = f2bf(v.w);
    *(ushort4*)&As[r * LD + k4 * 4] = o;
  }
  __syncthreads();
  int w = t >> 6, l = t & 63;
  int lr = l & 15, lk = l >> 4;
  f32x4 at[4][2], ar[4][2];
#pragma unroll
  for (int mb = 0; mb < 4; ++mb)
#pragma unroll
    for (int nb = 0; nb < 2; ++nb)
#pragma unroll
      for (int q = 0; q < 4; ++q) { at[mb][nb][q] = 0.f; ar[mb][nb][q] = 0.f; }
#pragma unroll
  for (int ks = 0; ks < 4; ++ks) {
    int koff = ks * 32 + lk * 8;
    bf16x8 a[4], bl[2], br[2];
#pragma unroll
    for (int mb = 0; mb < 4; ++mb)
      a[mb] = *(const bf16x8*)&As[(mb * 16 + lr) * LD + koff];
#pragma unroll
    for (int nb = 0; nb < 2; ++nb) {
      int c = w * 32 + nb * 16 + lr;
      bl[nb] = *(const bf16x8*)&wl[c * 128 + koff];
      br[nb] = *(const bf16x8*)&wr[c * 128 + koff];
    }
#pragma unroll
    for (int mb = 0; mb < 4; ++mb)
#pragma unroll
      for (int nb = 0; nb < 2; ++nb) {
        at[mb][nb] = __builtin_amdgcn_mfma_f32_16x16x32_bf16(a[mb], bl[nb], at[mb][nb], 0, 0, 0);
        ar[mb][nb] = __builtin_amdgcn_mfma_f32_16x16x32_bf16(a[mb], br[nb], ar[mb][nb], 0, 0, 0);
      }
  }
#pragma unroll
  for (int mb = 0; mb < 4; ++mb) {
    int r = row0 + mb * 16 + lk * 4;
#pragma unroll
    for (int nb = 0; nb < 2; ++nb) {
      int c = w * 32 + nb * 16 + lr;
#pragma unroll
      for (int j = 0; j < 4; ++j) {
        if (r + j < N) {
          t1[(size_t)(r + j) * 128 + c] = f2fp8(at[mb][nb][j]);
          r1[(size_t)(r + j) * 128 + c] = f2bf(ar[mb][nb][j]);
        }
      }
    }
  }
}

// layer-2: y2 = fp8(h1 @ W2l.T), r2 = bf16(h1 @ W2r.T); B = wb2 from global
__global__ __launch_bounds__(TPB, 4) void k_lin2(
    const unsigned short* __restrict__ h1, const unsigned short* __restrict__ w2,
    unsigned char* __restrict__ y2, unsigned short* __restrict__ r2, int N) {
  __shared__ unsigned short As[64 * LD];
  int t = threadIdx.x;
  int row0 = blockIdx.x * 64;
  for (int i = t * 8; i < 64 * 128; i += TPB * 8) {
    int r = i >> 7, k8 = i & 127;
    int gr = row0 + r;
    bf16x8 v;
    if (gr < N) v = *(const bf16x8*)&h1[(size_t)gr * 128 + k8];
    else { for (int q = 0; q < 8; ++q) v[q] = 0; }
    *(bf16x8*)&As[r * LD + k8] = v;
  }
  __syncthreads();
  int w = t >> 6, l = t & 63;
  int lr = l & 15, lk = l >> 4;
  f32x4 acc[4][2];
#pragma unroll
  for (int mb = 0; mb < 4; ++mb)
#pragma unroll
    for (int nb = 0; nb < 2; ++nb)
#pragma unroll
      for (int q = 0; q < 4; ++q) acc[mb][nb][q] = 0.f;
#pragma unroll
  for (int ks = 0; ks < 4; ++ks) {
    int koff = ks * 32 + lk * 8;
    bf16x8 a[4], bfr[2];
#pragma unroll
    for (int mb = 0; mb < 4; ++mb)
      a[mb] = *(const bf16x8*)&As[(mb * 16 + lr) * LD + koff];
#pragma unroll
    for (int nb = 0; nb < 2; ++nb) {
      int c = w * 32 + nb * 16 + lr;
      bfr[nb] = *(const bf16x8*)&w2[c * 128 + koff];
    }
#pragma unroll
    for (int mb = 0; mb < 4; ++mb)
#pragma unroll
      for (int nb = 0; nb < 2; ++nb)
        acc[mb][nb] = __builtin_amdgcn_mfma_f32_16x16x32_bf16(a[mb], bfr[nb], acc[mb][nb], 0, 0, 0);
  }
#pragma unroll
  for (int mb = 0; mb < 4; ++mb) {
    int r = row0 + mb * 16 + lk * 4;
#pragma unroll
    for (int nb = 0; nb < 2; ++nb) {
      int c = w * 32 + nb * 16 + lr;
#pragma unroll
      for (int j = 0; j < 4; ++j) {
        if (r + j < N) {
          if (c < 64) y2[(size_t)(r + j) * 64 + c] = f2fp8(acc[mb][nb][j]);
          else        r2[(size_t)(r + j) * 64 + (c - 64)] = f2bf(acc[mb][nb][j]);
        }
      }
    }
  }
}

// ---------------- gather(fp8) + h1 (wave per node, 4-deep unroll) -----------
__global__ void k_aggh1(const unsigned char* __restrict__ t1,
                        const unsigned short* __restrict__ r1,
                        const int* __restrict__ rowptr, const int* __restrict__ col,
                        const float* __restrict__ b1,
                        unsigned short* __restrict__ h1, int n) {
  int wid = (int)(((size_t)blockIdx.x * blockDim.x + threadIdx.x) >> 6);
  int l = threadIdx.x & 63;
  if (wid >= n) return;
  int rp0 = rowptr[wid], rp1 = rowptr[wid + 1];
  int g = l >> 4, s = l & 15;
  float acc[8];
#pragma unroll
  for (int q = 0; q < 8; ++q) acc[q] = 0.f;
  int j = rp0 + g;
  for (; j + 12 < rp1; j += 16) {
    int c0 = col[j], c1 = col[j + 4], c2 = col[j + 8], c3 = col[j + 12];
    uint2 v0 = *(const uint2*)&t1[(size_t)c0 * 128 + s * 8];
    uint2 v1 = *(const uint2*)&t1[(size_t)c1 * 128 + s * 8];
    uint2 v2 = *(const uint2*)&t1[(size_t)c2 * 128 + s * 8];
    uint2 v3 = *(const uint2*)&t1[(size_t)c3 * 128 + s * 8];
    fp8x8_acc(v0, acc); fp8x8_acc(v1, acc);
    fp8x8_acc(v2, acc); fp8x8_acc(v3, acc);
  }
  for (; j + 4 < rp1; j += 8) {
    int c0 = col[j], c1 = col[j + 4];
    uint2 v0 = *(const uint2*)&t1[(size_t)c0 * 128 + s * 8];
    uint2 v1 = *(const uint2*)&t1[(size_t)c1 * 128 + s * 8];
    fp8x8_acc(v0, acc); fp8x8_acc(v1, acc);
  }
  if (j < rp1) {
    uint2 v0 = *(const uint2*)&t1[(size_t)col[j] * 128 + s * 8];
    fp8x8_acc(v0, acc);
  }
#pragma unroll
  for (int q = 0; q < 8; ++q) {
    acc[q] += __shfl_xor(acc[q], 16, 64);
    acc[q] += __shfl_xor(acc[q], 32, 64);
  }
  if (g == 0) {
    int d = rp1 - rp0;
    float inv = 1.f / (float)(d > 1 ? d : 1);
    bf16x8 rr = *(const bf16x8*)&r1[(size_t)wid * 128 + s * 8];
    float4 bb0 = *(const float4*)&b1[s * 8];
    float4 bb1 = *(const float4*)&b1[s * 8 + 4];
    float bbv[8] = {bb0.x, bb0.y, bb0.z, bb0.w, bb1.x, bb1.y, bb1.z, bb1.w};
    bf16x8 o;
#pragma unroll
    for (int q = 0; q < 8; ++q) {
      float h = acc[q] * inv + bf2f((unsigned short)rr[q]) + bbv[q];
      h = h > 0.f ? h : 0.f;
      o[q] = (short)f2bf(h);
    }
    *(bf16x8*)&h1[(size_t)wid * 128 + s * 8] = o;
  }
}

// ---------------- gather(fp8) + h2 + classifier (wave per node) -------------
__global__ void k_agghead(const unsigned char* __restrict__ y2,
                          const unsigned short* __restrict__ r2,
                          const int* __restrict__ rowptr, const int* __restrict__ col,
                          const float* __restrict__ b2, const float* __restrict__ Wc,
                          const float* __restrict__ bc, float* __restrict__ out, int n) {
  int wid = (int)(((size_t)blockIdx.x * blockDim.x + threadIdx.x) >> 6);
  int l = threadIdx.x & 63;
  if (wid >= n) return;
  int rp0 = rowptr[wid], rp1 = rowptr[wid + 1];
  int g = l >> 3, s = l & 7;
  float acc[8];
#pragma unroll
  for (int q = 0; q < 8; ++q) acc[q] = 0.f;
  int j = rp0 + g;
  for (; j + 8 < rp1; j += 16) {
    int c0 = col[j], c1 = col[j + 8];
    uint2 v0 = *(const uint2*)&y2[(size_t)c0 * 64 + s * 8];
    uint2 v1 = *(const uint2*)&y2[(size_t)c1 * 64 + s * 8];
    fp8x8_acc(v0, acc); fp8x8_acc(v1, acc);
  }
  if (j < rp1) {
    uint2 v0 = *(const uint2*)&y2[(size_t)col[j] * 64 + s * 8];
    fp8x8_acc(v0, acc);
  }
#pragma unroll
  for (int q = 0; q < 8; ++q) {
    acc[q] += __shfl_xor(acc[q], 8, 64);
    acc[q] += __shfl_xor(acc[q], 16, 64);
    acc[q] += __shfl_xor(acc[q], 32, 64);
  }
  if (g == 0) {
    int d = rp1 - rp0;
    float inv = 1.f / (float)(d > 1 ? d : 1);
    bf16x8 rr = *(const bf16x8*)&r2[(size_t)wid * 64 + s * 8];
    float4 bb0 = *(const float4*)&b2[s * 8];
    float4 bb1 = *(const float4*)&b2[s * 8 + 4];
    float bbv[8] = {bb0.x, bb0.y, bb0.z, bb0.w, bb1.x, bb1.y, bb1.z, bb1.w};
    float4 wc0 = *(const float4*)&Wc[s * 8];
    float4 wc1 = *(const float4*)&Wc[s * 8 + 4];
    float wcv[8] = {wc0.x, wc0.y, wc0.z, wc0.w, wc1.x, wc1.y, wc1.z, wc1.w};
    float p = 0.f;
#pragma unroll
    for (int q = 0; q < 8; ++q) {
      float h = acc[q] * inv + bf2f((unsigned short)rr[q]) + bbv[q];
      h = h > 0.f ? h : 0.f;
      p += h * wcv[q];
    }
    p += __shfl_xor(p, 1, 64);
    p += __shfl_xor(p, 2, 64);
    p += __shfl_xor(p, 4, 64);
    if (s == 0) out[wid] = p + bc[0];
  }
}

extern "C" void kernel_launch(void* const* d_in, const int* in_sizes, int n_in,
                              void* d_out, int out_size, void* d_ws, size_t ws_size,
                              hipStream_t stream) {
  const float* x   = (const float*)d_in[0];
  const int*   ei  = (const int*)d_in[1];
  const float* W1l = (const float*)d_in[2];
  const float* W1r = (const float*)d_in[3];
  const float* b1  = (const float*)d_in[4];
  const float* W2l = (const float*)d_in[5];
  const float* W2r = (const float*)d_in[6];
  const float* b2  = (const float*)d_in[7];
  const float* Wc  = (const float*)d_in[8];
  const float* bc  = (const float*)d_in[9];
  float* logits = (float*)d_out;

  const int N = in_sizes[0] / 128;  // 100000
  const int E = in_sizes[1] / 2;    // 1600000
  const int NB = (N + 127) >> 7;    // 782 buckets (128 nodes each)
  const int EC = (E + NWG - 1) / NWG;  // 3125 edges per chunk WG

  char* ws = (char*)d_ws;
  size_t o = 0;
  auto alloc = [&](size_t bytes) { size_t r = o; o += (bytes + 511) & ~511ULL; return r; };
  size_t o_rp    = alloc((size_t)(N + 1) * 4);
  size_t o_bcc   = alloc((size_t)(2 * NB) * 4);  // bcnt | bcur (one memset)
  size_t o_col   = alloc((size_t)E * 4);
  size_t o_ebuf  = alloc((size_t)E * 4);         // packed 4B edges
  size_t o_wb    = alloc((size_t)(3 * 128 * 128) * 2);  // wb1l|wb1r|wb2 bf16
  size_t o_t1    = alloc((size_t)N * 128);       // fp8 gather table L1 (12.8MB)
  size_t o_r1    = alloc((size_t)N * 128 * 2);   // bf16 root transform L1
  size_t o_h1    = alloc((size_t)N * 128 * 2);   // bf16 h1
  size_t o_y2    = alloc((size_t)N * 64);        // fp8 gather table L2 (6.4MB)
  size_t o_r2    = alloc((size_t)N * 64 * 2);    // bf16 root transform L2
  if (o > ws_size) return;

  int* rp    = (int*)(ws + o_rp);
  int* bcnt  = (int*)(ws + o_bcc);
  int* bcur  = bcnt + NB;
  int* col   = (int*)(ws + o_col);
  int* ebuf  = (int*)(ws + o_ebuf);
  unsigned short* wb1l = (unsigned short*)(ws + o_wb);
  unsigned short* wb1r = wb1l + 128 * 128;
  unsigned short* wb2  = wb1r + 128 * 128;
  unsigned char*  t1 = (unsigned char*)(ws + o_t1);
  unsigned short* r1 = (unsigned short*)(ws + o_r1);
  unsigned short* h1 = (unsigned short*)(ws + o_h1);
  unsigned char*  y2 = (unsigned char*)(ws + o_y2);
  unsigned short* r2 = (unsigned short*)(ws + o_r2);

  const int* esrc = ei;
  const int* edst = ei + E;

  int gtiles = (N + 63) / 64;                               // 1563
  int nodeblocks = (int)(((size_t)N * 64 + TPB - 1) / TPB); // 25000

  hipMemsetAsync(bcnt, 0, (size_t)(2 * NB) * 4, stream);
  k_wprep<<<192, TPB, 0, stream>>>(W1l, W1r, W2l, W2r, wb1l, wb1r, wb2);
  k_bcount<<<NWG, TPB, (size_t)NB * 4, stream>>>(edst, bcnt, E, NB, EC);
  k_lin1<<<gtiles, TPB, 0, stream>>>(x, wb1l, wb1r, t1, r1, N);
  k_bscatter<<<NWG, TPB, 0, stream>>>(esrc, edst, bcnt, bcur, ebuf, E, NB, EC);
  k_bcsr<<<NB, TPB, 0, stream>>>(ebuf, bcnt, rp, col, N, NB);
  k_aggh1<<<nodeblocks, TPB, 0, stream>>>(t1, r1, rp, col, b1, h1, N);
  k_lin2<<<gtiles, TPB, 0, stream>>>(h1, wb2, y2, r2, N);
  k_agghead<<<nodeblocks, TPB, 0, stream>>>(y2, r2, rp, col, b2, Wc, bc, logits, N);
}

// Round 11
// 188.246 us; speedup vs baseline: 1.2489x; 1.1346x over previous
//
#include <hip/hip_runtime.h>

// GraphSAGE 2-layer + classifier on MI355X (gfx950).
// fp8-e4m3 gather tables, bf16 MFMA GEMMs (global-resident bf16 weights),
// self-counting fixed-capacity bucket CSR (no pre-count pass).
//
//   k_wprep:  W->bf16 (98KB, L2-resident) + zero bcur
//   k_lin1:   t1 = fp8(x @ W1l.T), r1 = bf16(x @ W1r.T)  single pass, dual acc
//   k_bscatter: LDS-stage chunk, LDS hist, one global atomicAdd per
//               (block,bucket) reserves a run in the bucket's FIXED 2560-slot
//               region of ebuf -> packed (dstlocal<<17|src) appended
//   k_bcsr:   per 128-node bucket: e0 = prefix(bcur), degree count + scan ->
//             rowptr, col scatter
//   k_aggh1:  wave/node: h1 = bf16(relu(gather-sum_fp8(t1)/deg + r1 + b1))
//   k_lin2:   y2 = fp8(h1 @ W2l.T), r2 = bf16(h1 @ W2r.T)
//   k_agghead: wave/node: logit = relu(gather-sum_fp8(y2)/deg + r2 + b2).Wc+bc

static constexpr int TPB = 256;
static constexpr int NWG = 512;    // edge-chunk workgroups
static constexpr int ECMAX = 3200; // >= E/NWG = 3125
static constexpr int NBMAX = 1024; // >= ceil(N/128) = 782
static constexpr int BCAP = 2560;  // bucket capacity (mean 2048, ~11 sigma)

typedef __attribute__((ext_vector_type(8))) short bf16x8;
typedef __attribute__((ext_vector_type(4))) float f32x4;
typedef __attribute__((ext_vector_type(2))) float f32x2;

#if __has_builtin(__builtin_amdgcn_cvt_pk_f32_fp8) && __has_builtin(__builtin_amdgcn_cvt_pk_fp8_f32)
#define FP8_HW 1
#endif

__device__ __forceinline__ unsigned short f2bf(float f) {
  union { float f; unsigned u; } v; v.f = f;
  unsigned r = v.u + 0x7FFFu + ((v.u >> 16) & 1u);  // RNE
  return (unsigned short)(r >> 16);
}
__device__ __forceinline__ float bf2f(unsigned short h) {
  union { unsigned u; float f; } v; v.u = ((unsigned)h) << 16;
  return v.f;
}

// ---- fp8 e4m3fn helpers (HW cvt preferred; manual fallback) ----
__device__ __forceinline__ float fp82f_sw(unsigned u) {
  unsigned e = (u >> 3) & 15u, m = u & 7u;
  float f;
  if (e == 0) f = (float)m * 0.001953125f;  // m * 2^-9
  else {
    union { unsigned u; float f; } v;
    v.u = ((e + 120u) << 23) | (m << 20);
    f = v.f;
  }
  return (u & 0x80u) ? -f : f;
}

__device__ __forceinline__ unsigned char f2fp8(float f) {
#ifdef FP8_HW
  return (unsigned char)(__builtin_amdgcn_cvt_pk_fp8_f32(f, f, 0, false) & 0xFF);
#else
  union { float f; unsigned u; } v; v.f = f;
  unsigned s = (v.u >> 24) & 0x80u;
  unsigned a = v.u & 0x7FFFFFFFu;
  if (a >= 0x43E00000u) return (unsigned char)(s | 0x7Eu);  // clamp to 448
  int e32 = (int)(a >> 23);
  if (e32 < 121) {  // subnormal region (< 2^-6)
    float sc = __builtin_fabsf(f) * 512.0f;  // 2^9
    int m = (int)(sc + 0.5f);
    if (m >= 8) return (unsigned char)(s | 0x08u);
    return (unsigned char)(s | (unsigned)m);
  }
  unsigned m = a & 0x7FFFFFu;
  unsigned lsb = (m >> 20) & 1u;
  m += 0x7FFFFu + lsb;
  unsigned e8 = (unsigned)(e32 - 120);
  if (m >= 0x800000u) { m -= 0x800000u; e8 += 1; }
  if (e8 >= 16) return (unsigned char)(s | 0x7Eu);
  return (unsigned char)(s | (e8 << 3) | (m >> 20));
#endif
}

// accumulate 8 fp8 (as uint2) into acc[8]
__device__ __forceinline__ void fp8x8_acc(uint2 v, float* acc) {
#ifdef FP8_HW
  f32x2 a0 = __builtin_amdgcn_cvt_pk_f32_fp8(v.x, false);
  f32x2 a1 = __builtin_amdgcn_cvt_pk_f32_fp8(v.x, true);
  f32x2 a2 = __builtin_amdgcn_cvt_pk_f32_fp8(v.y, false);
  f32x2 a3 = __builtin_amdgcn_cvt_pk_f32_fp8(v.y, true);
  acc[0] += a0[0]; acc[1] += a0[1]; acc[2] += a1[0]; acc[3] += a1[1];
  acc[4] += a2[0]; acc[5] += a2[1]; acc[6] += a3[0]; acc[7] += a3[1];
#else
  acc[0] += fp82f_sw(v.x & 255); acc[1] += fp82f_sw((v.x >> 8) & 255);
  acc[2] += fp82f_sw((v.x >> 16) & 255); acc[3] += fp82f_sw(v.x >> 24);
  acc[4] += fp82f_sw(v.y & 255); acc[5] += fp82f_sw((v.y >> 8) & 255);
  acc[6] += fp82f_sw((v.y >> 16) & 255); acc[7] += fp82f_sw(v.y >> 24);
#endif
}

// ---------------- weight prep (f32->bf16) + zero bcur ----------------
__global__ void k_wprep(const float* __restrict__ W1l, const float* __restrict__ W1r,
                        const float* __restrict__ W2l, const float* __restrict__ W2r,
                        unsigned short* __restrict__ wb1l,
                        unsigned short* __restrict__ wb1r,
                        unsigned short* __restrict__ wb2,
                        int* __restrict__ bcur, int NB) {
  int i = blockIdx.x * blockDim.x + threadIdx.x;
  if (i < NB) bcur[i] = 0;
  if (i < 16384) wb1l[i] = f2bf(W1l[i]);
  else if (i < 32768) wb1r[i - 16384] = f2bf(W1r[i - 16384]);
  else if (i < 40960) wb2[i - 32768] = f2bf(W2l[i - 32768]);        // rows 0-63
  else if (i < 49152) wb2[8192 + i - 40960] = f2bf(W2r[i - 40960]); // rows 64-127
}

// ---------------- self-counting bucket scatter (fixed-capacity) -------------
__global__ __launch_bounds__(TPB) void k_bscatter(
    const int* __restrict__ src, const int* __restrict__ dst,
    int* __restrict__ bcur, int* __restrict__ ebuf, int E, int NB, int EC) {
  __shared__ int pv[ECMAX];
  __shared__ unsigned short kb[ECMAX];
  __shared__ int lhist[NBMAX];
  __shared__ int lcur[NBMAX];
  int t = threadIdx.x;
  for (int b = t; b < NB; b += TPB) lhist[b] = 0;
  int base = blockIdx.x * EC;
  int cnt = min(EC, E - base);
  __syncthreads();
  for (int i = t; i < cnt; i += TPB) {
    int sv = src[base + i], dv = dst[base + i];
    int b = dv >> 7;
    kb[i] = (unsigned short)b;
    pv[i] = ((dv & 127) << 17) | sv;
    atomicAdd(&lhist[b], 1);
  }
  __syncthreads();
  for (int b = t; b < NB; b += TPB) {
    int c = lhist[b];
    lcur[b] = c ? (b * BCAP + atomicAdd(&bcur[b], c)) : 0;
  }
  __syncthreads();
  for (int i = t; i < cnt; i += TPB) {
    int b = kb[i];
    int pos = atomicAdd(&lcur[b], 1);
    if (pos < (b + 1) * BCAP) ebuf[pos] = pv[i];  // overflow guard (never hit)
  }
}

// ---------------- per-bucket CSR finalize (128 nodes per WG) ----------------
__global__ __launch_bounds__(TPB) void k_bcsr(
    const int* __restrict__ ebuf, const int* __restrict__ bcur,
    int* __restrict__ rowptr, int* __restrict__ col, int N, int NB) {
  __shared__ int deg[128], sscan[128], lcur[128], red[TPB];
  int b = blockIdx.x, t = threadIdx.x;
  int part = 0;
  for (int i = t; i < b; i += TPB) part += min(bcur[i], BCAP);
  red[t] = part; __syncthreads();
  for (int off = TPB / 2; off > 0; off >>= 1) {
    if (t < off) red[t] += red[t + off];
    __syncthreads();
  }
  int e0 = red[0];
  int mycnt = min(bcur[b], BCAP);
  int e1 = e0 + mycnt;
  int ebase = b * BCAP;
  if (t < 128) deg[t] = 0;
  __syncthreads();
  for (int i = t; i < mycnt; i += TPB)
    atomicAdd(&deg[ebuf[ebase + i] >> 17], 1);
  __syncthreads();
  if (t < 128) sscan[t] = deg[t];
  __syncthreads();
  for (int off = 1; off < 128; off <<= 1) {
    int x = 0;
    if (t < 128 && t >= off) x = sscan[t - off];
    __syncthreads();
    if (t < 128) sscan[t] += x;
    __syncthreads();
  }
  if (t < 128) {
    int excl = sscan[t] - deg[t];
    int node0 = (b << 7) + t;
    if (node0 < N) rowptr[node0] = e0 + excl;
    lcur[t] = e0 + excl;
  }
  if (b == NB - 1 && t == 0) rowptr[N] = e1;
  __syncthreads();
  for (int i = t; i < mycnt; i += TPB) {
    int pvv = ebuf[ebase + i];
    int pos = atomicAdd(&lcur[pvv >> 17], 1);
    col[pos] = pvv & 0x1FFFF;
  }
}

// ---------------- MFMA GEMMs: A in LDS, B direct from global bf16 -----------
static constexpr int LD = 136;  // padded bf16 leading dim (2-way aliasing = free)

// layer-1: single pass, dual accumulators (t1 fp8 + r1 bf16), B from global
__global__ __launch_bounds__(TPB, 4) void k_lin1(
    const float* __restrict__ X, const unsigned short* __restrict__ wl,
    const unsigned short* __restrict__ wr, unsigned char* __restrict__ t1,
    unsigned short* __restrict__ r1, int N) {
  __shared__ unsigned short As[64 * LD];
  int t = threadIdx.x;
  int row0 = blockIdx.x * 64;
  for (int i = t; i < 64 * 32; i += TPB) {
    int r = i >> 5, k4 = i & 31;
    int gr = row0 + r;
    float4 v;
    if (gr < N) v = *(const float4*)&X[(size_t)gr * 128 + k4 * 4];
    else { v.x = v.y = v.z = v.w = 0.f; }
    ushort4 o; o.x = f2bf(v.x); o.y = f2bf(v.y); o.z = f2bf(v.z); o.w = f2bf(v.w);
    *(ushort4*)&As[r * LD + k4 * 4] = o;
  }
  __syncthreads();
  int w = t >> 6, l = t & 63;
  int lr = l & 15, lk = l >> 4;
  f32x4 at[4][2], ar[4][2];
#pragma unroll
  for (int mb = 0; mb < 4; ++mb)
#pragma unroll
    for (int nb = 0; nb < 2; ++nb)
#pragma unroll
      for (int q = 0; q < 4; ++q) { at[mb][nb][q] = 0.f; ar[mb][nb][q] = 0.f; }
#pragma unroll
  for (int ks = 0; ks < 4; ++ks) {
    int koff = ks * 32 + lk * 8;
    bf16x8 a[4], bl[2], br[2];
#pragma unroll
    for (int mb = 0; mb < 4; ++mb)
      a[mb] = *(const bf16x8*)&As[(mb * 16 + lr) * LD + koff];
#pragma unroll
    for (int nb = 0; nb < 2; ++nb) {
      int c = w * 32 + nb * 16 + lr;
      bl[nb] = *(const bf16x8*)&wl[c * 128 + koff];
      br[nb] = *(const bf16x8*)&wr[c * 128 + koff];
    }
#pragma unroll
    for (int mb = 0; mb < 4; ++mb)
#pragma unroll
      for (int nb = 0; nb < 2; ++nb) {
        at[mb][nb] = __builtin_amdgcn_mfma_f32_16x16x32_bf16(a[mb], bl[nb], at[mb][nb], 0, 0, 0);
        ar[mb][nb] = __builtin_amdgcn_mfma_f32_16x16x32_bf16(a[mb], br[nb], ar[mb][nb], 0, 0, 0);
      }
  }
#pragma unroll
  for (int mb = 0; mb < 4; ++mb) {
    int r = row0 + mb * 16 + lk * 4;
#pragma unroll
    for (int nb = 0; nb < 2; ++nb) {
      int c = w * 32 + nb * 16 + lr;
#pragma unroll
      for (int j = 0; j < 4; ++j) {
        if (r + j < N) {
          t1[(size_t)(r + j) * 128 + c] = f2fp8(at[mb][nb][j]);
          r1[(size_t)(r + j) * 128 + c] = f2bf(ar[mb][nb][j]);
        }
      }
    }
  }
}

// layer-2: y2 = fp8(h1 @ W2l.T), r2 = bf16(h1 @ W2r.T); B = wb2 from global
__global__ __launch_bounds__(TPB, 4) void k_lin2(
    const unsigned short* __restrict__ h1, const unsigned short* __restrict__ w2,
    unsigned char* __restrict__ y2, unsigned short* __restrict__ r2, int N) {
  __shared__ unsigned short As[64 * LD];
  int t = threadIdx.x;
  int row0 = blockIdx.x * 64;
  for (int i = t * 8; i < 64 * 128; i += TPB * 8) {
    int r = i >> 7, k8 = i & 127;
    int gr = row0 + r;
    bf16x8 v;
    if (gr < N) v = *(const bf16x8*)&h1[(size_t)gr * 128 + k8];
    else { for (int q = 0; q < 8; ++q) v[q] = 0; }
    *(bf16x8*)&As[r * LD + k8] = v;
  }
  __syncthreads();
  int w = t >> 6, l = t & 63;
  int lr = l & 15, lk = l >> 4;
  f32x4 acc[4][2];
#pragma unroll
  for (int mb = 0; mb < 4; ++mb)
#pragma unroll
    for (int nb = 0; nb < 2; ++nb)
#pragma unroll
      for (int q = 0; q < 4; ++q) acc[mb][nb][q] = 0.f;
#pragma unroll
  for (int ks = 0; ks < 4; ++ks) {
    int koff = ks * 32 + lk * 8;
    bf16x8 a[4], bfr[2];
#pragma unroll
    for (int mb = 0; mb < 4; ++mb)
      a[mb] = *(const bf16x8*)&As[(mb * 16 + lr) * LD + koff];
#pragma unroll
    for (int nb = 0; nb < 2; ++nb) {
      int c = w * 32 + nb * 16 + lr;
      bfr[nb] = *(const bf16x8*)&w2[c * 128 + koff];
    }
#pragma unroll
    for (int mb = 0; mb < 4; ++mb)
#pragma unroll
      for (int nb = 0; nb < 2; ++nb)
        acc[mb][nb] = __builtin_amdgcn_mfma_f32_16x16x32_bf16(a[mb], bfr[nb], acc[mb][nb], 0, 0, 0);
  }
#pragma unroll
  for (int mb = 0; mb < 4; ++mb) {
    int r = row0 + mb * 16 + lk * 4;
#pragma unroll
    for (int nb = 0; nb < 2; ++nb) {
      int c = w * 32 + nb * 16 + lr;
#pragma unroll
      for (int j = 0; j < 4; ++j) {
        if (r + j < N) {
          if (c < 64) y2[(size_t)(r + j) * 64 + c] = f2fp8(acc[mb][nb][j]);
          else        r2[(size_t)(r + j) * 64 + (c - 64)] = f2bf(acc[mb][nb][j]);
        }
      }
    }
  }
}

// ---------------- gather(fp8) + h1 (wave per node, 4-deep unroll) -----------
__global__ void k_aggh1(const unsigned char* __restrict__ t1,
                        const unsigned short* __restrict__ r1,
                        const int* __restrict__ rowptr, const int* __restrict__ col,
                        const float* __restrict__ b1,
                        unsigned short* __restrict__ h1, int n) {
  int wid = (int)(((size_t)blockIdx.x * blockDim.x + threadIdx.x) >> 6);
  int l = threadIdx.x & 63;
  if (wid >= n) return;
  int rp0 = rowptr[wid], rp1 = rowptr[wid + 1];
  int g = l >> 4, s = l & 15;
  float acc[8];
#pragma unroll
  for (int q = 0; q < 8; ++q) acc[q] = 0.f;
  int j = rp0 + g;
  for (; j + 12 < rp1; j += 16) {
    int c0 = col[j], c1 = col[j + 4], c2 = col[j + 8], c3 = col[j + 12];
    uint2 v0 = *(const uint2*)&t1[(size_t)c0 * 128 + s * 8];
    uint2 v1 = *(const uint2*)&t1[(size_t)c1 * 128 + s * 8];
    uint2 v2 = *(const uint2*)&t1[(size_t)c2 * 128 + s * 8];
    uint2 v3 = *(const uint2*)&t1[(size_t)c3 * 128 + s * 8];
    fp8x8_acc(v0, acc); fp8x8_acc(v1, acc);
    fp8x8_acc(v2, acc); fp8x8_acc(v3, acc);
  }
  for (; j + 4 < rp1; j += 8) {
    int c0 = col[j], c1 = col[j + 4];
    uint2 v0 = *(const uint2*)&t1[(size_t)c0 * 128 + s * 8];
    uint2 v1 = *(const uint2*)&t1[(size_t)c1 * 128 + s * 8];
    fp8x8_acc(v0, acc); fp8x8_acc(v1, acc);
  }
  if (j < rp1) {
    uint2 v0 = *(const uint2*)&t1[(size_t)col[j] * 128 + s * 8];
    fp8x8_acc(v0, acc);
  }
#pragma unroll
  for (int q = 0; q < 8; ++q) {
    acc[q] += __shfl_xor(acc[q], 16, 64);
    acc[q] += __shfl_xor(acc[q], 32, 64);
  }
  if (g == 0) {
    int d = rp1 - rp0;
    float inv = 1.f / (float)(d > 1 ? d : 1);
    bf16x8 rr = *(const bf16x8*)&r1[(size_t)wid * 128 + s * 8];
    float4 bb0 = *(const float4*)&b1[s * 8];
    float4 bb1 = *(const float4*)&b1[s * 8 + 4];
    float bbv[8] = {bb0.x, bb0.y, bb0.z, bb0.w, bb1.x, bb1.y, bb1.z, bb1.w};
    bf16x8 o;
#pragma unroll
    for (int q = 0; q < 8; ++q) {
      float h = acc[q] * inv + bf2f((unsigned short)rr[q]) + bbv[q];
      h = h > 0.f ? h : 0.f;
      o[q] = (short)f2bf(h);
    }
    *(bf16x8*)&h1[(size_t)wid * 128 + s * 8] = o;
  }
}

// ---------------- gather(fp8) + h2 + classifier (wave per node) -------------
__global__ void k_agghead(const unsigned char* __restrict__ y2,
                          const unsigned short* __restrict__ r2,
                          const int* __restrict__ rowptr, const int* __restrict__ col,
                          const float* __restrict__ b2, const float* __restrict__ Wc,
                          const float* __restrict__ bc, float* __restrict__ out, int n) {
  int wid = (int)(((size_t)blockIdx.x * blockDim.x + threadIdx.x) >> 6);
  int l = threadIdx.x & 63;
  if (wid >= n) return;
  int rp0 = rowptr[wid], rp1 = rowptr[wid + 1];
  int g = l >> 3, s = l & 7;
  float acc[8];
#pragma unroll
  for (int q = 0; q < 8; ++q) acc[q] = 0.f;
  int j = rp0 + g;
  for (; j + 8 < rp1; j += 16) {
    int c0 = col[j], c1 = col[j + 8];
    uint2 v0 = *(const uint2*)&y2[(size_t)c0 * 64 + s * 8];
    uint2 v1 = *(const uint2*)&y2[(size_t)c1 * 64 + s * 8];
    fp8x8_acc(v0, acc); fp8x8_acc(v1, acc);
  }
  if (j < rp1) {
    uint2 v0 = *(const uint2*)&y2[(size_t)col[j] * 64 + s * 8];
    fp8x8_acc(v0, acc);
  }
#pragma unroll
  for (int q = 0; q < 8; ++q) {
    acc[q] += __shfl_xor(acc[q], 8, 64);
    acc[q] += __shfl_xor(acc[q], 16, 64);
    acc[q] += __shfl_xor(acc[q], 32, 64);
  }
  if (g == 0) {
    int d = rp1 - rp0;
    float inv = 1.f / (float)(d > 1 ? d : 1);
    bf16x8 rr = *(const bf16x8*)&r2[(size_t)wid * 64 + s * 8];
    float4 bb0 = *(const float4*)&b2[s * 8];
    float4 bb1 = *(const float4*)&b2[s * 8 + 4];
    float bbv[8] = {bb0.x, bb0.y, bb0.z, bb0.w, bb1.x, bb1.y, bb1.z, bb1.w};
    float4 wc0 = *(const float4*)&Wc[s * 8];
    float4 wc1 = *(const float4*)&Wc[s * 8 + 4];
    float wcv[8] = {wc0.x, wc0.y, wc0.z, wc0.w, wc1.x, wc1.y, wc1.z, wc1.w};
    float p = 0.f;
#pragma unroll
    for (int q = 0; q < 8; ++q) {
      float h = acc[q] * inv + bf2f((unsigned short)rr[q]) + bbv[q];
      h = h > 0.f ? h : 0.f;
      p += h * wcv[q];
    }
    p += __shfl_xor(p, 1, 64);
    p += __shfl_xor(p, 2, 64);
    p += __shfl_xor(p, 4, 64);
    if (s == 0) out[wid] = p + bc[0];
  }
}

extern "C" void kernel_launch(void* const* d_in, const int* in_sizes, int n_in,
                              void* d_out, int out_size, void* d_ws, size_t ws_size,
                              hipStream_t stream) {
  const float* x   = (const float*)d_in[0];
  const int*   ei  = (const int*)d_in[1];
  const float* W1l = (const float*)d_in[2];
  const float* W1r = (const float*)d_in[3];
  const float* b1  = (const float*)d_in[4];
  const float* W2l = (const float*)d_in[5];
  const float* W2r = (const float*)d_in[6];
  const float* b2  = (const float*)d_in[7];
  const float* Wc  = (const float*)d_in[8];
  const float* bc  = (const float*)d_in[9];
  float* logits = (float*)d_out;

  const int N = in_sizes[0] / 128;  // 100000
  const int E = in_sizes[1] / 2;    // 1600000
  const int NB = (N + 127) >> 7;    // 782 buckets (128 nodes each)
  const int EC = (E + NWG - 1) / NWG;  // 3125 edges per chunk WG

  char* ws = (char*)d_ws;
  size_t o = 0;
  auto alloc = [&](size_t bytes) { size_t r = o; o += (bytes + 511) & ~511ULL; return r; };
  size_t o_rp    = alloc((size_t)(N + 1) * 4);
  size_t o_bcur  = alloc((size_t)NB * 4);
  size_t o_col   = alloc((size_t)E * 4);
  size_t o_ebuf  = alloc((size_t)NB * BCAP * 4);  // fixed-capacity buckets (8MB)
  size_t o_wb    = alloc((size_t)(3 * 128 * 128) * 2);  // wb1l|wb1r|wb2 bf16
  size_t o_t1    = alloc((size_t)N * 128);       // fp8 gather table L1 (12.8MB)
  size_t o_r1    = alloc((size_t)N * 128 * 2);   // bf16 root transform L1
  size_t o_h1    = alloc((size_t)N * 128 * 2);   // bf16 h1
  size_t o_y2    = alloc((size_t)N * 64);        // fp8 gather table L2 (6.4MB)
  size_t o_r2    = alloc((size_t)N * 64 * 2);    // bf16 root transform L2
  if (o > ws_size) return;

  int* rp    = (int*)(ws + o_rp);
  int* bcur  = (int*)(ws + o_bcur);
  int* col   = (int*)(ws + o_col);
  int* ebuf  = (int*)(ws + o_ebuf);
  unsigned short* wb1l = (unsigned short*)(ws + o_wb);
  unsigned short* wb1r = wb1l + 128 * 128;
  unsigned short* wb2  = wb1r + 128 * 128;
  unsigned char*  t1 = (unsigned char*)(ws + o_t1);
  unsigned short* r1 = (unsigned short*)(ws + o_r1);
  unsigned short* h1 = (unsigned short*)(ws + o_h1);
  unsigned char*  y2 = (unsigned char*)(ws + o_y2);
  unsigned short* r2 = (unsigned short*)(ws + o_r2);

  const int* esrc = ei;
  const int* edst = ei + E;

  int gtiles = (N + 63) / 64;                               // 1563
  int nodeblocks = (int)(((size_t)N * 64 + TPB - 1) / TPB); // 25000

  k_wprep<<<192, TPB, 0, stream>>>(W1l, W1r, W2l, W2r, wb1l, wb1r, wb2, bcur, NB);
  k_lin1<<<gtiles, TPB, 0, stream>>>(x, wb1l, wb1r, t1, r1, N);
  k_bscatter<<<NWG, TPB, 0, stream>>>(esrc, edst, bcur, ebuf, E, NB, EC);
  k_bcsr<<<NB, TPB, 0, stream>>>(ebuf, bcur, rp, col, N, NB);
  k_aggh1<<<nodeblocks, TPB, 0, stream>>>(t1, r1, rp, col, b1, h1, N);
  k_lin2<<<gtiles, TPB, 0, stream>>>(h1, wb2, y2, r2, N);
  k_agghead<<<nodeblocks, TPB, 0, stream>>>(y2, r2, rp, col, b2, Wc, bc, logits, N);
}

// Round 12
// 184.958 us; speedup vs baseline: 1.2711x; 1.0178x over previous
//
#include <hip/hip_runtime.h>

// GraphSAGE 2-layer + classifier on MI355X (gfx950).
// fp8-e4m3 gather tables (pk_add f32x2 accumulate), bf16 MFMA GEMMs
// (global-resident bf16 weights), self-counting bucket CSR, lin1||bscatter
// grid fusion.
//
//   k_wprep:    W->bf16 (98KB, L2-resident) + zero bcur
//   k_lin1_bsc: blocks [0,NWG): bucket-scatter edges (LDS stage, fixed-cap
//               append via one global atomic per (block,bucket))
//               blocks [NWG,+gtiles): t1 = fp8(x @ W1l.T), r1 = bf16(x @ W1r.T)
//   k_bcsr:     per 128-node bucket: e0 = prefix(bcur); degree count + scan ->
//               rowptr; col scatter
//   k_aggh1:    wave/node: h1 = bf16(relu(gather-sum_fp8(t1)/deg + r1 + b1))
//   k_lin2:     y2 = fp8(h1 @ W2l.T), r2 = bf16(h1 @ W2r.T)
//   k_agghead:  wave/node: logit = relu(gather-sum_fp8(y2)/deg + r2 + b2).Wc+bc

static constexpr int TPB = 256;
static constexpr int NWG = 512;    // edge-chunk workgroups
static constexpr int ECMAX = 3200; // >= E/NWG = 3125
static constexpr int NBMAX = 1024; // >= ceil(N/128) = 782
static constexpr int BCAP = 2560;  // bucket capacity (mean 2048, ~11 sigma)

typedef __attribute__((ext_vector_type(8))) short bf16x8;
typedef __attribute__((ext_vector_type(4))) float f32x4;
typedef __attribute__((ext_vector_type(2))) float f32x2;

#if __has_builtin(__builtin_amdgcn_cvt_pk_f32_fp8) && __has_builtin(__builtin_amdgcn_cvt_pk_fp8_f32)
#define FP8_HW 1
#endif

__device__ __forceinline__ unsigned short f2bf(float f) {
  union { float f; unsigned u; } v; v.f = f;
  unsigned r = v.u + 0x7FFFu + ((v.u >> 16) & 1u);  // RNE
  return (unsigned short)(r >> 16);
}
__device__ __forceinline__ float bf2f(unsigned short h) {
  union { unsigned u; float f; } v; v.u = ((unsigned)h) << 16;
  return v.f;
}

// ---- fp8 e4m3fn helpers (HW cvt preferred; manual fallback) ----
__device__ __forceinline__ float fp82f_sw(unsigned u) {
  unsigned e = (u >> 3) & 15u, m = u & 7u;
  float f;
  if (e == 0) f = (float)m * 0.001953125f;  // m * 2^-9
  else {
    union { unsigned u; float f; } v;
    v.u = ((e + 120u) << 23) | (m << 20);
    f = v.f;
  }
  return (u & 0x80u) ? -f : f;
}

__device__ __forceinline__ unsigned char f2fp8(float f) {
#ifdef FP8_HW
  return (unsigned char)(__builtin_amdgcn_cvt_pk_fp8_f32(f, f, 0, false) & 0xFF);
#else
  union { float f; unsigned u; } v; v.f = f;
  unsigned s = (v.u >> 24) & 0x80u;
  unsigned a = v.u & 0x7FFFFFFFu;
  if (a >= 0x43E00000u) return (unsigned char)(s | 0x7Eu);  // clamp to 448
  int e32 = (int)(a >> 23);
  if (e32 < 121) {  // subnormal region (< 2^-6)
    float sc = __builtin_fabsf(f) * 512.0f;  // 2^9
    int m = (int)(sc + 0.5f);
    if (m >= 8) return (unsigned char)(s | 0x08u);
    return (unsigned char)(s | (unsigned)m);
  }
  unsigned m = a & 0x7FFFFFu;
  unsigned lsb = (m >> 20) & 1u;
  m += 0x7FFFFu + lsb;
  unsigned e8 = (unsigned)(e32 - 120);
  if (m >= 0x800000u) { m -= 0x800000u; e8 += 1; }
  if (e8 >= 16) return (unsigned char)(s | 0x7Eu);
  return (unsigned char)(s | (e8 << 3) | (m >> 20));
#endif
}

// accumulate 8 fp8 (uint2) into 4 packed f32x2 accumulators (v_pk_add_f32)
__device__ __forceinline__ void fp8x8_acc2(uint2 v, f32x2* a) {
#ifdef FP8_HW
  a[0] += __builtin_amdgcn_cvt_pk_f32_fp8(v.x, false);
  a[1] += __builtin_amdgcn_cvt_pk_f32_fp8(v.x, true);
  a[2] += __builtin_amdgcn_cvt_pk_f32_fp8(v.y, false);
  a[3] += __builtin_amdgcn_cvt_pk_f32_fp8(v.y, true);
#else
  a[0][0] += fp82f_sw(v.x & 255); a[0][1] += fp82f_sw((v.x >> 8) & 255);
  a[1][0] += fp82f_sw((v.x >> 16) & 255); a[1][1] += fp82f_sw(v.x >> 24);
  a[2][0] += fp82f_sw(v.y & 255); a[2][1] += fp82f_sw((v.y >> 8) & 255);
  a[3][0] += fp82f_sw((v.y >> 16) & 255); a[3][1] += fp82f_sw(v.y >> 24);
#endif
}

// ---------------- weight prep (f32->bf16) + zero bcur ----------------
__global__ void k_wprep(const float* __restrict__ W1l, const float* __restrict__ W1r,
                        const float* __restrict__ W2l, const float* __restrict__ W2r,
                        unsigned short* __restrict__ wb1l,
                        unsigned short* __restrict__ wb1r,
                        unsigned short* __restrict__ wb2,
                        int* __restrict__ bcur, int NB) {
  int i = blockIdx.x * blockDim.x + threadIdx.x;
  if (i < NB) bcur[i] = 0;
  if (i < 16384) wb1l[i] = f2bf(W1l[i]);
  else if (i < 32768) wb1r[i - 16384] = f2bf(W1r[i - 16384]);
  else if (i < 40960) wb2[i - 32768] = f2bf(W2l[i - 32768]);        // rows 0-63
  else if (i < 49152) wb2[8192 + i - 40960] = f2bf(W2r[i - 40960]); // rows 64-127
}

// ---------------- MFMA geometry ----------------
static constexpr int LD = 136;  // padded bf16 leading dim (2-way aliasing = free)
static constexpr int SMEM_INTS = 6848;  // 27392B union: bscatter 27392 | lin1 As 17408

// ---------------- fused lin1 (MFMA) || bucket scatter ----------------
__global__ __launch_bounds__(TPB, 4) void k_lin1_bsc(
    const float* __restrict__ X, const unsigned short* __restrict__ wl,
    const unsigned short* __restrict__ wr, unsigned char* __restrict__ t1,
    unsigned short* __restrict__ r1, int N,
    const int* __restrict__ src, const int* __restrict__ dst,
    int* __restrict__ bcur, int* __restrict__ ebuf, int E, int NB, int EC) {
  __shared__ int smem[SMEM_INTS];
  int bid = blockIdx.x;
  int t = threadIdx.x;
  if (bid < NWG) {
    // ---- bucket-scatter role ----
    int* pv = smem;                                      // ECMAX ints
    unsigned short* kb = (unsigned short*)(smem + ECMAX); // ECMAX ushort
    int* lhist = smem + ECMAX + ((ECMAX + 1) >> 1);      // NBMAX
    int* lcur  = lhist + NBMAX;                          // NBMAX
    for (int b = t; b < NB; b += TPB) lhist[b] = 0;
    int base = bid * EC;
    int cnt = min(EC, E - base);
    __syncthreads();
    for (int i = t; i < cnt; i += TPB) {
      int sv = src[base + i], dv = dst[base + i];
      int b = dv >> 7;
      kb[i] = (unsigned short)b;
      pv[i] = ((dv & 127) << 17) | sv;
      atomicAdd(&lhist[b], 1);
    }
    __syncthreads();
    for (int b = t; b < NB; b += TPB) {
      int c = lhist[b];
      lcur[b] = c ? (b * BCAP + atomicAdd(&bcur[b], c)) : 0;
    }
    __syncthreads();
    for (int i = t; i < cnt; i += TPB) {
      int b = kb[i];
      int pos = atomicAdd(&lcur[b], 1);
      if (pos < (b + 1) * BCAP) ebuf[pos] = pv[i];  // overflow guard (never hit)
    }
    return;
  }
  // ---- lin1 role: t1 = fp8(x@W1l.T), r1 = bf16(x@W1r.T), dual acc ----
  unsigned short* As = (unsigned short*)smem;  // 64*LD ushort = 17408B
  int row0 = (bid - NWG) * 64;
  for (int i = t; i < 64 * 32; i += TPB) {
    int r = i >> 5, k4 = i & 31;
    int gr = row0 + r;
    float4 v;
    if (gr < N) v = *(const float4*)&X[(size_t)gr * 128 + k4 * 4];
    else { v.x = v.y = v.z = v.w = 0.f; }
    ushort4 o; o.x = f2bf(v.x); o.y = f2bf(v.y); o.z = f2bf(v.z); o.w = f2bf(v.w);
    *(ushort4*)&As[r * LD + k4 * 4] = o;
  }
  __syncthreads();
  int w = t >> 6, l = t & 63;
  int lr = l & 15, lk = l >> 4;
  f32x4 at[4][2], ar[4][2];
#pragma unroll
  for (int mb = 0; mb < 4; ++mb)
#pragma unroll
    for (int nb = 0; nb < 2; ++nb)
#pragma unroll
      for (int q = 0; q < 4; ++q) { at[mb][nb][q] = 0.f; ar[mb][nb][q] = 0.f; }
#pragma unroll
  for (int ks = 0; ks < 4; ++ks) {
    int koff = ks * 32 + lk * 8;
    bf16x8 a[4], bl[2], br[2];
#pragma unroll
    for (int mb = 0; mb < 4; ++mb)
      a[mb] = *(const bf16x8*)&As[(mb * 16 + lr) * LD + koff];
#pragma unroll
    for (int nb = 0; nb < 2; ++nb) {
      int c = w * 32 + nb * 16 + lr;
      bl[nb] = *(const bf16x8*)&wl[c * 128 + koff];
      br[nb] = *(const bf16x8*)&wr[c * 128 + koff];
    }
#pragma unroll
    for (int mb = 0; mb < 4; ++mb)
#pragma unroll
      for (int nb = 0; nb < 2; ++nb) {
        at[mb][nb] = __builtin_amdgcn_mfma_f32_16x16x32_bf16(a[mb], bl[nb], at[mb][nb], 0, 0, 0);
        ar[mb][nb] = __builtin_amdgcn_mfma_f32_16x16x32_bf16(a[mb], br[nb], ar[mb][nb], 0, 0, 0);
      }
  }
#pragma unroll
  for (int mb = 0; mb < 4; ++mb) {
    int r = row0 + mb * 16 + lk * 4;
#pragma unroll
    for (int nb = 0; nb < 2; ++nb) {
      int c = w * 32 + nb * 16 + lr;
#pragma unroll
      for (int j = 0; j < 4; ++j) {
        if (r + j < N) {
          t1[(size_t)(r + j) * 128 + c] = f2fp8(at[mb][nb][j]);
          r1[(size_t)(r + j) * 128 + c] = f2bf(ar[mb][nb][j]);
        }
      }
    }
  }
}

// ---------------- per-bucket CSR finalize (128 nodes per WG) ----------------
__global__ __launch_bounds__(TPB) void k_bcsr(
    const int* __restrict__ ebuf, const int* __restrict__ bcur,
    int* __restrict__ rowptr, int* __restrict__ col, int N, int NB) {
  __shared__ int deg[128], sscan[128], lcur[128], red[TPB];
  int b = blockIdx.x, t = threadIdx.x;
  int part = 0;
  for (int i = t; i < b; i += TPB) part += min(bcur[i], BCAP);
  red[t] = part; __syncthreads();
  for (int off = TPB / 2; off > 0; off >>= 1) {
    if (t < off) red[t] += red[t + off];
    __syncthreads();
  }
  int e0 = red[0];
  int mycnt = min(bcur[b], BCAP);
  int e1 = e0 + mycnt;
  int ebase = b * BCAP;
  if (t < 128) deg[t] = 0;
  __syncthreads();
  for (int i = t; i < mycnt; i += TPB)
    atomicAdd(&deg[ebuf[ebase + i] >> 17], 1);
  __syncthreads();
  if (t < 128) sscan[t] = deg[t];
  __syncthreads();
  for (int off = 1; off < 128; off <<= 1) {
    int x = 0;
    if (t < 128 && t >= off) x = sscan[t - off];
    __syncthreads();
    if (t < 128) sscan[t] += x;
    __syncthreads();
  }
  if (t < 128) {
    int excl = sscan[t] - deg[t];
    int node0 = (b << 7) + t;
    if (node0 < N) rowptr[node0] = e0 + excl;
    lcur[t] = e0 + excl;
  }
  if (b == NB - 1 && t == 0) rowptr[N] = e1;
  __syncthreads();
  for (int i = t; i < mycnt; i += TPB) {
    int pvv = ebuf[ebase + i];
    int pos = atomicAdd(&lcur[pvv >> 17], 1);
    col[pos] = pvv & 0x1FFFF;
  }
}

// ---------------- gather(fp8) + h1 (wave per node, 4-deep, pk_add) ----------
__global__ void k_aggh1(const unsigned char* __restrict__ t1,
                        const unsigned short* __restrict__ r1,
                        const int* __restrict__ rowptr, const int* __restrict__ col,
                        const float* __restrict__ b1,
                        unsigned short* __restrict__ h1, int n) {
  int wid = (int)(((size_t)blockIdx.x * blockDim.x + threadIdx.x) >> 6);
  int l = threadIdx.x & 63;
  if (wid >= n) return;
  int rp0 = rowptr[wid], rp1 = rowptr[wid + 1];
  int g = l >> 4, s = l & 15;
  f32x2 acc2[4];
#pragma unroll
  for (int q = 0; q < 4; ++q) { acc2[q][0] = 0.f; acc2[q][1] = 0.f; }
  int j = rp0 + g;
  for (; j + 12 < rp1; j += 16) {
    int c0 = col[j], c1 = col[j + 4], c2 = col[j + 8], c3 = col[j + 12];
    uint2 v0 = *(const uint2*)&t1[(size_t)c0 * 128 + s * 8];
    uint2 v1 = *(const uint2*)&t1[(size_t)c1 * 128 + s * 8];
    uint2 v2 = *(const uint2*)&t1[(size_t)c2 * 128 + s * 8];
    uint2 v3 = *(const uint2*)&t1[(size_t)c3 * 128 + s * 8];
    fp8x8_acc2(v0, acc2); fp8x8_acc2(v1, acc2);
    fp8x8_acc2(v2, acc2); fp8x8_acc2(v3, acc2);
  }
  for (; j + 4 < rp1; j += 8) {
    int c0 = col[j], c1 = col[j + 4];
    uint2 v0 = *(const uint2*)&t1[(size_t)c0 * 128 + s * 8];
    uint2 v1 = *(const uint2*)&t1[(size_t)c1 * 128 + s * 8];
    fp8x8_acc2(v0, acc2); fp8x8_acc2(v1, acc2);
  }
  if (j < rp1) {
    uint2 v0 = *(const uint2*)&t1[(size_t)col[j] * 128 + s * 8];
    fp8x8_acc2(v0, acc2);
  }
#pragma unroll
  for (int q = 0; q < 4; ++q)
#pragma unroll
    for (int k = 0; k < 2; ++k) {
      acc2[q][k] += __shfl_xor(acc2[q][k], 16, 64);
      acc2[q][k] += __shfl_xor(acc2[q][k], 32, 64);
    }
  if (g == 0) {
    int d = rp1 - rp0;
    float inv = 1.f / (float)(d > 1 ? d : 1);
    bf16x8 rr = *(const bf16x8*)&r1[(size_t)wid * 128 + s * 8];
    float4 bb0 = *(const float4*)&b1[s * 8];
    float4 bb1 = *(const float4*)&b1[s * 8 + 4];
    float bbv[8] = {bb0.x, bb0.y, bb0.z, bb0.w, bb1.x, bb1.y, bb1.z, bb1.w};
    bf16x8 o;
#pragma unroll
    for (int q = 0; q < 8; ++q) {
      float h = acc2[q >> 1][q & 1] * inv + bf2f((unsigned short)rr[q]) + bbv[q];
      h = h > 0.f ? h : 0.f;
      o[q] = (short)f2bf(h);
    }
    *(bf16x8*)&h1[(size_t)wid * 128 + s * 8] = o;
  }
}

// layer-2: y2 = fp8(h1 @ W2l.T), r2 = bf16(h1 @ W2r.T); B = wb2 from global
__global__ __launch_bounds__(TPB, 4) void k_lin2(
    const unsigned short* __restrict__ h1, const unsigned short* __restrict__ w2,
    unsigned char* __restrict__ y2, unsigned short* __restrict__ r2, int N) {
  __shared__ unsigned short As[64 * LD];
  int t = threadIdx.x;
  int row0 = blockIdx.x * 64;
  for (int i = t * 8; i < 64 * 128; i += TPB * 8) {
    int r = i >> 7, k8 = i & 127;
    int gr = row0 + r;
    bf16x8 v;
    if (gr < N) v = *(const bf16x8*)&h1[(size_t)gr * 128 + k8];
    else { for (int q = 0; q < 8; ++q) v[q] = 0; }
    *(bf16x8*)&As[r * LD + k8] = v;
  }
  __syncthreads();
  int w = t >> 6, l = t & 63;
  int lr = l & 15, lk = l >> 4;
  f32x4 acc[4][2];
#pragma unroll
  for (int mb = 0; mb < 4; ++mb)
#pragma unroll
    for (int nb = 0; nb < 2; ++nb)
#pragma unroll
      for (int q = 0; q < 4; ++q) acc[mb][nb][q] = 0.f;
#pragma unroll
  for (int ks = 0; ks < 4; ++ks) {
    int koff = ks * 32 + lk * 8;
    bf16x8 a[4], bfr[2];
#pragma unroll
    for (int mb = 0; mb < 4; ++mb)
      a[mb] = *(const bf16x8*)&As[(mb * 16 + lr) * LD + koff];
#pragma unroll
    for (int nb = 0; nb < 2; ++nb) {
      int c = w * 32 + nb * 16 + lr;
      bfr[nb] = *(const bf16x8*)&w2[c * 128 + koff];
    }
#pragma unroll
    for (int mb = 0; mb < 4; ++mb)
#pragma unroll
      for (int nb = 0; nb < 2; ++nb)
        acc[mb][nb] = __builtin_amdgcn_mfma_f32_16x16x32_bf16(a[mb], bfr[nb], acc[mb][nb], 0, 0, 0);
  }
#pragma unroll
  for (int mb = 0; mb < 4; ++mb) {
    int r = row0 + mb * 16 + lk * 4;
#pragma unroll
    for (int nb = 0; nb < 2; ++nb) {
      int c = w * 32 + nb * 16 + lr;
#pragma unroll
      for (int j = 0; j < 4; ++j) {
        if (r + j < N) {
          if (c < 64) y2[(size_t)(r + j) * 64 + c] = f2fp8(acc[mb][nb][j]);
          else        r2[(size_t)(r + j) * 64 + (c - 64)] = f2bf(acc[mb][nb][j]);
        }
      }
    }
  }
}

// ---------------- gather(fp8) + h2 + classifier (wave per node, pk_add) -----
__global__ void k_agghead(const unsigned char* __restrict__ y2,
                          const unsigned short* __restrict__ r2,
                          const int* __restrict__ rowptr, const int* __restrict__ col,
                          const float* __restrict__ b2, const float* __restrict__ Wc,
                          const float* __restrict__ bc, float* __restrict__ out, int n) {
  int wid = (int)(((size_t)blockIdx.x * blockDim.x + threadIdx.x) >> 6);
  int l = threadIdx.x & 63;
  if (wid >= n) return;
  int rp0 = rowptr[wid], rp1 = rowptr[wid + 1];
  int g = l >> 3, s = l & 7;
  f32x2 acc2[4];
#pragma unroll
  for (int q = 0; q < 4; ++q) { acc2[q][0] = 0.f; acc2[q][1] = 0.f; }
  int j = rp0 + g;
  for (; j + 8 < rp1; j += 16) {
    int c0 = col[j], c1 = col[j + 8];
    uint2 v0 = *(const uint2*)&y2[(size_t)c0 * 64 + s * 8];
    uint2 v1 = *(const uint2*)&y2[(size_t)c1 * 64 + s * 8];
    fp8x8_acc2(v0, acc2); fp8x8_acc2(v1, acc2);
  }
  if (j < rp1) {
    uint2 v0 = *(const uint2*)&y2[(size_t)col[j] * 64 + s * 8];
    fp8x8_acc2(v0, acc2);
  }
#pragma unroll
  for (int q = 0; q < 4; ++q)
#pragma unroll
    for (int k = 0; k < 2; ++k) {
      acc2[q][k] += __shfl_xor(acc2[q][k], 8, 64);
      acc2[q][k] += __shfl_xor(acc2[q][k], 16, 64);
      acc2[q][k] += __shfl_xor(acc2[q][k], 32, 64);
    }
  if (g == 0) {
    int d = rp1 - rp0;
    float inv = 1.f / (float)(d > 1 ? d : 1);
    bf16x8 rr = *(const bf16x8*)&r2[(size_t)wid * 64 + s * 8];
    float4 bb0 = *(const float4*)&b2[s * 8];
    float4 bb1 = *(const float4*)&b2[s * 8 + 4];
    float bbv[8] = {bb0.x, bb0.y, bb0.z, bb0.w, bb1.x, bb1.y, bb1.z, bb1.w};
    float4 wc0 = *(const float4*)&Wc[s * 8];
    float4 wc1 = *(const float4*)&Wc[s * 8 + 4];
    float wcv[8] = {wc0.x, wc0.y, wc0.z, wc0.w, wc1.x, wc1.y, wc1.z, wc1.w};
    float p = 0.f;
#pragma unroll
    for (int q = 0; q < 8; ++q) {
      float h = acc2[q >> 1][q & 1] * inv + bf2f((unsigned short)rr[q]) + bbv[q];
      h = h > 0.f ? h : 0.f;
      p += h * wcv[q];
    }
    p += __shfl_xor(p, 1, 64);
    p += __shfl_xor(p, 2, 64);
    p += __shfl_xor(p, 4, 64);
    if (s == 0) out[wid] = p + bc[0];
  }
}

extern "C" void kernel_launch(void* const* d_in, const int* in_sizes, int n_in,
                              void* d_out, int out_size, void* d_ws, size_t ws_size,
                              hipStream_t stream) {
  const float* x   = (const float*)d_in[0];
  const int*   ei  = (const int*)d_in[1];
  const float* W1l = (const float*)d_in[2];
  const float* W1r = (const float*)d_in[3];
  const float* b1  = (const float*)d_in[4];
  const float* W2l = (const float*)d_in[5];
  const float* W2r = (const float*)d_in[6];
  const float* b2  = (const float*)d_in[7];
  const float* Wc  = (const float*)d_in[8];
  const float* bc  = (const float*)d_in[9];
  float* logits = (float*)d_out;

  const int N = in_sizes[0] / 128;  // 100000
  const int E = in_sizes[1] / 2;    // 1600000
  const int NB = (N + 127) >> 7;    // 782 buckets (128 nodes each)
  const int EC = (E + NWG - 1) / NWG;  // 3125 edges per chunk WG

  char* ws = (char*)d_ws;
  size_t o = 0;
  auto alloc = [&](size_t bytes) { size_t r = o; o += (bytes + 511) & ~511ULL; return r; };
  size_t o_rp    = alloc((size_t)(N + 1) * 4);
  size_t o_bcur  = alloc((size_t)NB * 4);
  size_t o_col   = alloc((size_t)E * 4);
  size_t o_ebuf  = alloc((size_t)NB * BCAP * 4);  // fixed-capacity buckets (8MB)
  size_t o_wb    = alloc((size_t)(3 * 128 * 128) * 2);  // wb1l|wb1r|wb2 bf16
  size_t o_t1    = alloc((size_t)N * 128);       // fp8 gather table L1 (12.8MB)
  size_t o_r1    = alloc((size_t)N * 128 * 2);   // bf16 root transform L1
  size_t o_h1    = alloc((size_t)N * 128 * 2);   // bf16 h1
  size_t o_y2    = alloc((size_t)N * 64);        // fp8 gather table L2 (6.4MB)
  size_t o_r2    = alloc((size_t)N * 64 * 2);    // bf16 root transform L2
  if (o > ws_size) return;

  int* rp    = (int*)(ws + o_rp);
  int* bcur  = (int*)(ws + o_bcur);
  int* col   = (int*)(ws + o_col);
  int* ebuf  = (int*)(ws + o_ebuf);
  unsigned short* wb1l = (unsigned short*)(ws + o_wb);
  unsigned short* wb1r = wb1l + 128 * 128;
  unsigned short* wb2  = wb1r + 128 * 128;
  unsigned char*  t1 = (unsigned char*)(ws + o_t1);
  unsigned short* r1 = (unsigned short*)(ws + o_r1);
  unsigned short* h1 = (unsigned short*)(ws + o_h1);
  unsigned char*  y2 = (unsigned char*)(ws + o_y2);
  unsigned short* r2 = (unsigned short*)(ws + o_r2);

  const int* esrc = ei;
  const int* edst = ei + E;

  int gtiles = (N + 63) / 64;                               // 1563
  int nodeblocks = (int)(((size_t)N * 64 + TPB - 1) / TPB); // 25000

  k_wprep<<<192, TPB, 0, stream>>>(W1l, W1r, W2l, W2r, wb1l, wb1r, wb2, bcur, NB);
  k_lin1_bsc<<<NWG + gtiles, TPB, 0, stream>>>(
      x, wb1l, wb1r, t1, r1, N, esrc, edst, bcur, ebuf, E, NB, EC);
  k_bcsr<<<NB, TPB, 0, stream>>>(ebuf, bcur, rp, col, N, NB);
  k_aggh1<<<nodeblocks, TPB, 0, stream>>>(t1, r1, rp, col, b1, h1, N);
  k_lin2<<<gtiles, TPB, 0, stream>>>(h1, wb2, y2, r2, N);
  k_agghead<<<nodeblocks, TPB, 0, stream>>>(y2, r2, rp, col, b2, Wc, bc, logits, N);
}